// Round 1
// baseline (793.453 us; speedup 1.0000x reference)
//
#include <hip/hip_runtime.h>
#include <hip/hip_bf16.h>

#define B_ 2
#define T_ 2048
#define C_ 2048
#define H_ 32
#define HK_ 4
#define D_ 64

typedef __attribute__((ext_vector_type(4))) float f32x4;
typedef __attribute__((ext_vector_type(2))) float f32x2;
typedef __attribute__((ext_vector_type(8))) short bf16x8;

static __device__ __forceinline__ unsigned short f2bf(float f) {
  union { __hip_bfloat16 h; unsigned short s; } u;
  u.h = __float2bfloat16(f);
  return u.s;
}

// ---------------------------------------------------------------------------
// GEMM: C[M,N] = A[M,K] * W[N,K]^T   (f32 in/out, bf16 MFMA accumulate f32)
// 128x128 block tile, 4 waves (2x2), each wave 64x64 = 4x4 frags of 16x16x32.
// K-permutation-agnostic fragment loads: f(lane,i) = 8*(lane>>4)+i for both
// A and B operands -> exact product regardless of HW k-mapping.
// ---------------------------------------------------------------------------
#define LDSW 40  // 32 + 8 pad (shorts)

__global__ __launch_bounds__(256)
void gqa_gemm_bt(const float* __restrict__ A, const float* __restrict__ W,
                 float* __restrict__ C, int M, int N, int K) {
  __shared__ short As[128 * LDSW];
  __shared__ short Ws[128 * LDSW];

  const int tid  = threadIdx.x;
  const int lane = tid & 63;
  const int w    = tid >> 6;
  const int wm   = w >> 1, wn = w & 1;
  const int g    = lane >> 4;   // k-group 0..3
  const int lr   = lane & 15;   // row/col in fragment

  const int bm = blockIdx.y * 128;
  const int bn = blockIdx.x * 128;

  const int srow = tid >> 1;          // 0..127
  const int skc  = (tid & 1) * 16;    // 0 or 16

  const float* Ap = A + (size_t)(bm + srow) * K + skc;
  const float* Wp = W + (size_t)(bn + srow) * K + skc;

  f32x4 acc[4][4] = {};

  for (int k0 = 0; k0 < K; k0 += 32) {
    __syncthreads();
    f32x4 av0 = *(const f32x4*)(Ap + k0);
    f32x4 av1 = *(const f32x4*)(Ap + k0 + 4);
    f32x4 av2 = *(const f32x4*)(Ap + k0 + 8);
    f32x4 av3 = *(const f32x4*)(Ap + k0 + 12);
    f32x4 wv0 = *(const f32x4*)(Wp + k0);
    f32x4 wv1 = *(const f32x4*)(Wp + k0 + 4);
    f32x4 wv2 = *(const f32x4*)(Wp + k0 + 8);
    f32x4 wv3 = *(const f32x4*)(Wp + k0 + 12);

    short ab[16], wb[16];
#pragma unroll
    for (int j = 0; j < 4; j++) {
      ab[j]      = (short)f2bf(av0[j]);  ab[4 + j]  = (short)f2bf(av1[j]);
      ab[8 + j]  = (short)f2bf(av2[j]);  ab[12 + j] = (short)f2bf(av3[j]);
      wb[j]      = (short)f2bf(wv0[j]);  wb[4 + j]  = (short)f2bf(wv1[j]);
      wb[8 + j]  = (short)f2bf(wv2[j]);  wb[12 + j] = (short)f2bf(wv3[j]);
    }
    *(bf16x8*)&As[srow * LDSW + skc]     = *(bf16x8*)&ab[0];
    *(bf16x8*)&As[srow * LDSW + skc + 8] = *(bf16x8*)&ab[8];
    *(bf16x8*)&Ws[srow * LDSW + skc]     = *(bf16x8*)&wb[0];
    *(bf16x8*)&Ws[srow * LDSW + skc + 8] = *(bf16x8*)&wb[8];
    __syncthreads();

    bf16x8 af[4], wf[4];
#pragma unroll
    for (int m = 0; m < 4; m++)
      af[m] = *(const bf16x8*)&As[(wm * 64 + m * 16 + lr) * LDSW + g * 8];
#pragma unroll
    for (int n = 0; n < 4; n++)
      wf[n] = *(const bf16x8*)&Ws[(wn * 64 + n * 16 + lr) * LDSW + g * 8];
#pragma unroll
    for (int m = 0; m < 4; m++)
#pragma unroll
      for (int n = 0; n < 4; n++)
        acc[m][n] = __builtin_amdgcn_mfma_f32_16x16x32_bf16(af[m], wf[n], acc[m][n], 0, 0, 0);
  }

  // C/D layout: col = lane&15, row = 4*(lane>>4) + reg
#pragma unroll
  for (int m = 0; m < 4; m++) {
    const int row = bm + wm * 64 + m * 16 + g * 4;
#pragma unroll
    for (int n = 0; n < 4; n++) {
      const int col = bn + wn * 64 + n * 16 + lr;
#pragma unroll
      for (int r = 0; r < 4; r++)
        C[(size_t)(row + r) * N + col] = acc[m][n][r];
    }
  }
}

// ---------------------------------------------------------------------------
// RoPE on q: q_raw (B*T, H*D) f32 -> q_bf (B,H,T,D) bf16 (roped)
// ---------------------------------------------------------------------------
__global__ void gqa_rope_q(const float* __restrict__ qraw,
                           const float* __restrict__ cosT,
                           const float* __restrict__ sinT,
                           __hip_bfloat16* __restrict__ qb) {
  const int idx = blockIdx.x * blockDim.x + threadIdx.x; // B*T*H*32
  const int i  = idx & 31;
  const int h  = (idx >> 5) & 31;
  const int bt = idx >> 10;
  const int t  = bt & (T_ - 1);
  const int b  = bt >> 11;

  const f32x2 qv = *(const f32x2*)(qraw + (size_t)bt * (H_ * D_) + h * D_ + 2 * i);
  const float c = cosT[t * D_ + 2 * i];
  const float s = sinT[t * D_ + 2 * i];
  const float o0 = qv[0] * c - qv[1] * s;
  const float o1 = qv[1] * c + qv[0] * s;
  const size_t o = ((size_t)(b * H_ + h) * T_ + t) * D_ + 2 * i;
  unsigned int packed = (unsigned int)f2bf(o0) | ((unsigned int)f2bf(o1) << 16);
  *(unsigned int*)((unsigned short*)qb + o) = packed;
}

// ---------------------------------------------------------------------------
// RoPE on k: k_raw (B*T, Hk*D) f32 -> kout f32 (B,Hk,T,D) + k_bf bf16 same
// ---------------------------------------------------------------------------
__global__ void gqa_rope_k(const float* __restrict__ kraw,
                           const float* __restrict__ cosT,
                           const float* __restrict__ sinT,
                           float* __restrict__ kout,
                           __hip_bfloat16* __restrict__ kb) {
  const int idx = blockIdx.x * blockDim.x + threadIdx.x; // B*T*Hk*32
  const int i  = idx & 31;
  const int hk = (idx >> 5) & 3;
  const int bt = idx >> 7;
  const int t  = bt & (T_ - 1);
  const int b  = bt >> 11;

  const f32x2 kv = *(const f32x2*)(kraw + (size_t)bt * (HK_ * D_) + hk * D_ + 2 * i);
  const float c = cosT[t * D_ + 2 * i];
  const float s = sinT[t * D_ + 2 * i];
  const float o0 = kv[0] * c - kv[1] * s;
  const float o1 = kv[1] * c + kv[0] * s;
  const size_t o = ((size_t)(b * HK_ + hk) * T_ + t) * D_ + 2 * i;
  f32x2 ov; ov[0] = o0; ov[1] = o1;
  *(f32x2*)(kout + o) = ov;
  unsigned int packed = (unsigned int)f2bf(o0) | ((unsigned int)f2bf(o1) << 16);
  *(unsigned int*)((unsigned short*)kb + o) = packed;
}

// ---------------------------------------------------------------------------
// v reorder: v_raw (B*T, Hk*D) f32 -> vout f32 (B,Hk,T,D) + vT bf16 (B,Hk,D,T)
// ---------------------------------------------------------------------------
__global__ void gqa_v_reorder(const float* __restrict__ vraw,
                              float* __restrict__ vout,
                              __hip_bfloat16* __restrict__ vt) {
  const int idx = blockIdx.x * blockDim.x + threadIdx.x; // B*T*Hk*D
  const int d  = idx & 63;
  const int hk = (idx >> 6) & 3;
  const int bt = idx >> 8;
  const int t  = bt & (T_ - 1);
  const int b  = bt >> 11;

  const float v = vraw[(size_t)bt * (HK_ * D_) + hk * D_ + d];
  vout[((size_t)(b * HK_ + hk) * T_ + t) * D_ + d] = v;
  ((unsigned short*)vt)[((size_t)(b * HK_ + hk) * D_ + d) * T_ + t] = f2bf(v);
}

// ---------------------------------------------------------------------------
// Flash attention: qb (B,H,T,D) bf16, kb (B,Hk,T,D) bf16, vt (B,Hk,D,T) bf16
// -> o_ws (B*T, H*D) f32.  One wave per 16 queries; 64-key tiles; causal.
// ---------------------------------------------------------------------------
__global__ __launch_bounds__(256)
void gqa_attn(const __hip_bfloat16* __restrict__ qb,
              const __hip_bfloat16* __restrict__ kb,
              const __hip_bfloat16* __restrict__ vt,
              float* __restrict__ o_ws) {
  __shared__ short P_lds[4][16 * 72];

  const int tid  = threadIdx.x;
  const int lane = tid & 63;
  const int w    = tid >> 6;
  const int g    = lane >> 4;
  const int lr   = lane & 15;

  const int bh = blockIdx.y;     // b*H + h
  const int b  = bh >> 5;
  const int h  = bh & 31;
  const int hk = h >> 3;         // N_REP = 8
  const int qblock = blockIdx.x; // 0..T/64-1
  const int qbase  = qblock * 64 + w * 16;

  const unsigned short* qrow = (const unsigned short*)qb + ((size_t)bh * T_ + qbase + lr) * D_;
  const bf16x8 qf0 = *(const bf16x8*)(qrow + g * 8);
  const bf16x8 qf1 = *(const bf16x8*)(qrow + 32 + g * 8);

  const unsigned short* kbase = (const unsigned short*)kb + (size_t)(b * HK_ + hk) * T_ * D_;
  const unsigned short* vbase = (const unsigned short*)vt + (size_t)(b * HK_ + hk) * D_ * T_;
  short* myP = &P_lds[w][0];

  f32x4 oacc[4] = {};
  float mstat[4] = {-1e30f, -1e30f, -1e30f, -1e30f};
  float lstat[4] = {0.f, 0.f, 0.f, 0.f};

  for (int kb0 = 0; kb0 <= qblock * 64; kb0 += 64) {
    // ---- scores: 4 tiles of 16 keys ----
    f32x4 s[4];
#pragma unroll
    for (int t = 0; t < 4; t++) {
      const unsigned short* krow = kbase + (size_t)(kb0 + t * 16 + lr) * D_;
      bf16x8 kf0 = *(const bf16x8*)(krow + g * 8);
      bf16x8 kf1 = *(const bf16x8*)(krow + 32 + g * 8);
      f32x4 z = {};
      z = __builtin_amdgcn_mfma_f32_16x16x32_bf16(qf0, kf0, z, 0, 0, 0);
      z = __builtin_amdgcn_mfma_f32_16x16x32_bf16(qf1, kf1, z, 0, 0, 0);
      s[t] = z;
    }
    // ---- scale + causal mask ----
#pragma unroll
    for (int t = 0; t < 4; t++) {
#pragma unroll
      for (int r = 0; r < 4; r++) {
        const int q  = qbase + 4 * g + r;
        const int kk = kb0 + t * 16 + lr;
        const float sv = s[t][r] * 0.125f;
        s[t][r] = (kk <= q) ? sv : -1e30f;
      }
    }
    // ---- online softmax stats (row q = 4g+r lives on 16-lane group g) ----
    float mnew[4], alpha[4];
#pragma unroll
    for (int r = 0; r < 4; r++) {
      float mx = fmaxf(fmaxf(s[0][r], s[1][r]), fmaxf(s[2][r], s[3][r]));
      mx = fmaxf(mx, __shfl_xor(mx, 1));
      mx = fmaxf(mx, __shfl_xor(mx, 2));
      mx = fmaxf(mx, __shfl_xor(mx, 4));
      mx = fmaxf(mx, __shfl_xor(mx, 8));
      mnew[r]  = fmaxf(mstat[r], mx);
      alpha[r] = __expf(mstat[r] - mnew[r]);
      mstat[r] = mnew[r];
    }
#pragma unroll
    for (int r = 0; r < 4; r++) {
      float sum = 0.f;
#pragma unroll
      for (int t = 0; t < 4; t++) {
        const float p = __expf(s[t][r] - mnew[r]);
        s[t][r] = p;
        sum += p;
      }
      sum += __shfl_xor(sum, 1);
      sum += __shfl_xor(sum, 2);
      sum += __shfl_xor(sum, 4);
      sum += __shfl_xor(sum, 8);
      lstat[r] = lstat[r] * alpha[r] + sum;
    }
    // ---- P -> LDS (bf16), row = query-in-tile, col = key-in-tile ----
#pragma unroll
    for (int t = 0; t < 4; t++)
#pragma unroll
      for (int r = 0; r < 4; r++)
        myP[(4 * g + r) * 72 + t * 16 + lr] = (short)f2bf(s[t][r]);
    asm volatile("s_waitcnt lgkmcnt(0)" ::: "memory");
    __builtin_amdgcn_sched_barrier(0);

    // ---- rescale O ----
#pragma unroll
    for (int dt = 0; dt < 4; dt++)
#pragma unroll
      for (int r = 0; r < 4; r++)
        oacc[dt][r] *= alpha[r];

    // ---- PV: A = P (row=q, k=key), B = V via vT rows (col=d, k=key) ----
    bf16x8 pf0 = *(const bf16x8*)&myP[lr * 72 + g * 8];
    bf16x8 pf1 = *(const bf16x8*)&myP[lr * 72 + 32 + g * 8];
#pragma unroll
    for (int dt = 0; dt < 4; dt++) {
      const unsigned short* vrow = vbase + (size_t)(dt * 16 + lr) * T_ + kb0;
      bf16x8 vf0 = *(const bf16x8*)(vrow + g * 8);
      bf16x8 vf1 = *(const bf16x8*)(vrow + 32 + g * 8);
      oacc[dt] = __builtin_amdgcn_mfma_f32_16x16x32_bf16(pf0, vf0, oacc[dt], 0, 0, 0);
      oacc[dt] = __builtin_amdgcn_mfma_f32_16x16x32_bf16(pf1, vf1, oacc[dt], 0, 0, 0);
    }
  }

  // ---- normalize + store to o_ws (B*T, H*D) ----
  float inv[4];
#pragma unroll
  for (int r = 0; r < 4; r++) inv[r] = 1.0f / lstat[r];
#pragma unroll
  for (int dt = 0; dt < 4; dt++) {
#pragma unroll
    for (int r = 0; r < 4; r++) {
      const int q = qbase + 4 * g + r;
      o_ws[((size_t)b * T_ + q) * (H_ * D_) + h * D_ + dt * 16 + lr] = oacc[dt][r] * inv[r];
    }
  }
}

// ---------------------------------------------------------------------------
extern "C" void kernel_launch(void* const* d_in, const int* in_sizes, int n_in,
                              void* d_out, int out_size, void* d_ws, size_t ws_size,
                              hipStream_t stream) {
  const float* x    = (const float*)d_in[0];
  const float* cosT = (const float*)d_in[1];
  const float* sinT = (const float*)d_in[2];
  const float* wq   = (const float*)d_in[3];
  const float* wk   = (const float*)d_in[4];
  const float* wv   = (const float*)d_in[5];
  const float* wo   = (const float*)d_in[6];

  float* y    = (float*)d_out;                       // B*T*C
  float* kout = (float*)d_out + (size_t)B_ * T_ * C_;          // B*Hk*T*D
  float* vout = kout + (size_t)B_ * HK_ * T_ * D_;

  char* ws = (char*)d_ws;
  float* q_raw = (float*)ws;                                   // 33554432 B (reused as o_ws)
  float* o_ws  = q_raw;
  float* k_raw = (float*)(ws + 33554432);                      // 4194304 B
  float* v_raw = (float*)(ws + 33554432 + 4194304);            // 4194304 B
  __hip_bfloat16* q_bf = (__hip_bfloat16*)(ws + 41943040);     // 16777216 B
  __hip_bfloat16* k_bf = (__hip_bfloat16*)(ws + 58720256);     // 2097152 B
  __hip_bfloat16* v_t  = (__hip_bfloat16*)(ws + 60817408);     // 2097152 B

  const int M = B_ * T_;  // 4096
  dim3 blk(256);

  gqa_gemm_bt<<<dim3((H_ * D_) / 128, M / 128), blk, 0, stream>>>(x, wq, q_raw, M, H_ * D_, C_);
  gqa_gemm_bt<<<dim3((HK_ * D_) / 128, M / 128), blk, 0, stream>>>(x, wk, k_raw, M, HK_ * D_, C_);
  gqa_gemm_bt<<<dim3((HK_ * D_) / 128, M / 128), blk, 0, stream>>>(x, wv, v_raw, M, HK_ * D_, C_);

  gqa_rope_q<<<(B_ * T_ * H_ * 32) / 256, 256, 0, stream>>>(q_raw, cosT, sinT, q_bf);
  gqa_rope_k<<<(B_ * T_ * HK_ * 32) / 256, 256, 0, stream>>>(k_raw, cosT, sinT, kout, k_bf);
  gqa_v_reorder<<<(B_ * T_ * HK_ * D_) / 256, 256, 0, stream>>>(v_raw, vout, v_t);

  gqa_attn<<<dim3(T_ / 64, B_ * H_), 256, 0, stream>>>(q_bf, k_bf, v_t, o_ws);

  gqa_gemm_bt<<<dim3(C_ / 128, M / 128), blk, 0, stream>>>(o_ws, wo, y, M, C_, H_ * D_);
}

// Round 3
// 353.270 us; speedup vs baseline: 2.2460x; 2.2460x over previous
//
#include <hip/hip_runtime.h>
#include <hip/hip_bf16.h>

#define B_ 2
#define T_ 2048
#define C_ 2048
#define H_ 32
#define HK_ 4
#define D_ 64

typedef __attribute__((ext_vector_type(4)))  float f32x4;
typedef __attribute__((ext_vector_type(2)))  float f32x2;
typedef __attribute__((ext_vector_type(16))) float f32x16;
typedef __attribute__((ext_vector_type(8)))  short bf16x8;

static __device__ __forceinline__ unsigned short f2bf(float f) {
  union { __hip_bfloat16 h; unsigned short s; } u;
  u.h = __float2bfloat16(f);
  return u.s;
}
static __device__ __forceinline__ float bf2f(unsigned short s) {
  union { unsigned int u; float f; } u; u.u = ((unsigned int)s) << 16; return u.f;
}

#define GLD16(gp, lp) __builtin_amdgcn_global_load_lds( \
    (const __attribute__((address_space(1))) unsigned int*)(gp), \
    (__attribute__((address_space(3))) unsigned int*)(unsigned int)(uintptr_t)(lp), 16, 0, 0)

// ---------------------------------------------------------------------------
// f32 -> bf16 convert (vectorized)
// ---------------------------------------------------------------------------
__global__ void f32_to_bf16(const float* __restrict__ src, unsigned short* __restrict__ dst, int n4) {
  const int i = blockIdx.x * blockDim.x + threadIdx.x;
  if (i >= n4) return;
  f32x4 v = *(const f32x4*)(src + 4 * (size_t)i);
  ushort4 o;
  o.x = f2bf(v[0]); o.y = f2bf(v[1]); o.z = f2bf(v[2]); o.w = f2bf(v[3]);
  *(ushort4*)(dst + 4 * (size_t)i) = o;
}

// ---------------------------------------------------------------------------
// GEMM: C[M,N] = A[M,K]_bf16 * W[N,K]_bf16^T, m97-style: 128x128 tile, BK=32,
// global_load_lds width 16, linear [128][32] LDS (conflict-free frag reads).
// ---------------------------------------------------------------------------
template<bool BF16OUT>
__global__ __launch_bounds__(256)
void gemm_bf16(const unsigned short* __restrict__ A, const unsigned short* __restrict__ W,
               void* __restrict__ Cout, int M, int N, int K) {
  __shared__ unsigned short As[128 * 32];
  __shared__ unsigned short Ws[128 * 32];

  const int tid  = threadIdx.x;
  const int lane = tid & 63;
  const int w    = tid >> 6;
  const int wm   = w >> 1, wn = w & 1;
  const int g    = lane >> 4;
  const int lr   = lane & 15;

  const int bm = blockIdx.y * 128;
  const int bn = blockIdx.x * 128;

  // staging: wave w inst0 covers rows 16w..16w+15 (cols 0..31), inst1 rows +64
  const int srow = lane >> 2;        // 0..15
  const int scol = (lane & 3) * 8;   // 0,8,16,24
  const unsigned short* Ag = A + (size_t)(bm + 16 * w + srow) * K + scol;
  const unsigned short* Wg = W + (size_t)(bn + 16 * w + srow) * K + scol;
  unsigned short* Asl0 = &As[(16 * w) * 32];
  unsigned short* Asl1 = &As[(64 + 16 * w) * 32];
  unsigned short* Wsl0 = &Ws[(16 * w) * 32];
  unsigned short* Wsl1 = &Ws[(64 + 16 * w) * 32];

  f32x4 acc[4][4] = {};

  for (int k0 = 0; k0 < K; k0 += 32) {
    __syncthreads();
    GLD16(Ag + k0,                    Asl0);
    GLD16(Ag + (size_t)64 * K + k0,   Asl1);
    GLD16(Wg + k0,                    Wsl0);
    GLD16(Wg + (size_t)64 * K + k0,   Wsl1);
    __syncthreads();

    bf16x8 af[4], wf[4];
#pragma unroll
    for (int m = 0; m < 4; m++)
      af[m] = *(const bf16x8*)&As[(wm * 64 + m * 16 + lr) * 32 + g * 8];
#pragma unroll
    for (int n = 0; n < 4; n++)
      wf[n] = *(const bf16x8*)&Ws[(wn * 64 + n * 16 + lr) * 32 + g * 8];
#pragma unroll
    for (int m = 0; m < 4; m++)
#pragma unroll
      for (int n = 0; n < 4; n++)
        acc[m][n] = __builtin_amdgcn_mfma_f32_16x16x32_bf16(af[m], wf[n], acc[m][n], 0, 0, 0);
  }

  // C/D layout: col = lane&15, row = 4*(lane>>4) + reg
#pragma unroll
  for (int m = 0; m < 4; m++) {
    const int row = bm + wm * 64 + m * 16 + g * 4;
#pragma unroll
    for (int n = 0; n < 4; n++) {
      const int col = bn + wn * 64 + n * 16 + lr;
#pragma unroll
      for (int r = 0; r < 4; r++) {
        if (BF16OUT)
          ((unsigned short*)Cout)[(size_t)(row + r) * N + col] = f2bf(acc[m][n][r]);
        else
          ((float*)Cout)[(size_t)(row + r) * N + col] = acc[m][n][r];
      }
    }
  }
}

// ---------------------------------------------------------------------------
// RoPE q: qkv_bf (B*T, 2560) cols [0,2048) -> q_bf (B,H,T,D) bf16
// ---------------------------------------------------------------------------
__global__ void gqa_rope_q(const unsigned short* __restrict__ qkv,
                           const float* __restrict__ cosT,
                           const float* __restrict__ sinT,
                           unsigned short* __restrict__ qb) {
  const int idx = blockIdx.x * blockDim.x + threadIdx.x; // B*T*H*32
  const int i  = idx & 31;
  const int h  = (idx >> 5) & 31;
  const int bt = idx >> 10;
  const int t  = bt & (T_ - 1);
  const int b  = bt >> 11;

  const unsigned int qv = *(const unsigned int*)(qkv + (size_t)bt * 2560 + h * D_ + 2 * i);
  const float x1 = bf2f((unsigned short)(qv & 0xffff));
  const float x2 = bf2f((unsigned short)(qv >> 16));
  const float c = cosT[t * D_ + 2 * i];
  const float s = sinT[t * D_ + 2 * i];
  const float o0 = x1 * c - x2 * s;
  const float o1 = x2 * c + x1 * s;
  const size_t o = ((size_t)(b * H_ + h) * T_ + t) * D_ + 2 * i;
  *(unsigned int*)(qb + o) = (unsigned int)f2bf(o0) | ((unsigned int)f2bf(o1) << 16);
}

// ---------------------------------------------------------------------------
// RoPE k: qkv_bf cols [2048,2304) -> kout f32 (B,Hk,T,D) + k_bf bf16 same
// ---------------------------------------------------------------------------
__global__ void gqa_rope_k(const unsigned short* __restrict__ qkv,
                           const float* __restrict__ cosT,
                           const float* __restrict__ sinT,
                           float* __restrict__ kout,
                           unsigned short* __restrict__ kb) {
  const int idx = blockIdx.x * blockDim.x + threadIdx.x; // B*T*Hk*32
  const int i  = idx & 31;
  const int hk = (idx >> 5) & 3;
  const int bt = idx >> 7;
  const int t  = bt & (T_ - 1);
  const int b  = bt >> 11;

  const unsigned int kv = *(const unsigned int*)(qkv + (size_t)bt * 2560 + 2048 + hk * D_ + 2 * i);
  const float x1 = bf2f((unsigned short)(kv & 0xffff));
  const float x2 = bf2f((unsigned short)(kv >> 16));
  const float c = cosT[t * D_ + 2 * i];
  const float s = sinT[t * D_ + 2 * i];
  const float o0 = x1 * c - x2 * s;
  const float o1 = x2 * c + x1 * s;
  const size_t o = ((size_t)(b * HK_ + hk) * T_ + t) * D_ + 2 * i;
  f32x2 ov; ov[0] = o0; ov[1] = o1;
  *(f32x2*)(kout + o) = ov;
  *(unsigned int*)(kb + o) = (unsigned int)f2bf(o0) | ((unsigned int)f2bf(o1) << 16);
}

// ---------------------------------------------------------------------------
// v: qkv_bf cols [2304,2560) -> vout f32 (B,Hk,T,D) + vT bf16 (B,Hk,D,T)
// ---------------------------------------------------------------------------
__global__ void gqa_v_reorder(const unsigned short* __restrict__ qkv,
                              float* __restrict__ vout,
                              unsigned short* __restrict__ vt) {
  const int idx = blockIdx.x * blockDim.x + threadIdx.x; // B*T*Hk*D = 1048576
  const int d  = idx & 63;
  const int hk = (idx >> 6) & 3;
  const int bt = idx >> 8;
  const int t  = bt & (T_ - 1);
  const int b  = bt >> 11;

  const unsigned short v = qkv[(size_t)bt * 2560 + 2304 + hk * D_ + d];
  vout[((size_t)(b * HK_ + hk) * T_ + t) * D_ + d] = bf2f(v);
  vt[((size_t)(b * HK_ + hk) * D_ + d) * T_ + t] = v;
}

// ---------------------------------------------------------------------------
// Flash attention, 32x32 MFMA, swapped QK^T (S^T: query=lane&31 -> stats are
// per-lane scalars), PV as O^T = mfma(V^T-rows, P^T) with key-permuted V loads
// so P stays entirely in registers. One wave = 32 queries; KV tile = 64.
// ---------------------------------------------------------------------------
static __device__ __forceinline__ bf16x8 load_v44(const unsigned short* p) {
  short4 a = *(const short4*)p;
  short4 b = *(const short4*)(p + 8);
  bf16x8 r;
  r[0] = a.x; r[1] = a.y; r[2] = a.z; r[3] = a.w;
  r[4] = b.x; r[5] = b.y; r[6] = b.z; r[7] = b.w;
  return r;
}

__global__ __launch_bounds__(512)
void gqa_attn2(const unsigned short* __restrict__ qb,
               const unsigned short* __restrict__ kb,
               const unsigned short* __restrict__ vt,
               unsigned short* __restrict__ ob) {
  const int tid  = threadIdx.x;
  const int lane = tid & 63;
  const int w    = tid >> 6;      // 0..7
  const int qi   = lane & 31;
  const int hi   = lane >> 5;

  const int wave_id = blockIdx.x * 8 + w;   // 0..4095
  const int qt = 63 - (wave_id >> 6);       // heavy q-tiles first
  const int bh = wave_id & 63;
  const int b  = bh >> 5;
  const int h  = bh & 31;
  const int hk = h >> 3;

  const int qbase = qt * 32;
  const int qrow  = qbase + qi;

  // Q fragment (B operand): row q, d = 16c + 8hi + i
  const unsigned short* qptr = qb + ((size_t)bh * T_ + qrow) * D_ + 8 * hi;
  bf16x8 qf[4];
#pragma unroll
  for (int c = 0; c < 4; c++) qf[c] = *(const bf16x8*)(qptr + 16 * c);

  const unsigned short* kbase = kb + (size_t)(b * HK_ + hk) * T_ * D_;
  const unsigned short* vbase = vt + (size_t)(b * HK_ + hk) * D_ * T_;

  f32x16 o0 = {}, o1 = {};           // O^T: col q = lane&31; rows d
  float m = -1e30f, l = 0.f;

  const float SC = 0.125f * 1.44269504089f;  // 1/sqrt(D) * log2(e)

  const int ntiles = ((qbase + 31) >> 6) + 1;
  for (int it = 0; it < ntiles; ++it) {
    const int kb0 = it * 64;
    const bool last = (it == ntiles - 1);
    const bool has1 = (kb0 + 32 <= qbase + 31);

    // ---- QK^T swapped: S^T[key][q], A=K rows, B=Q rows ----
    const unsigned short* kp0 = kbase + (size_t)(kb0 + qi) * D_ + 8 * hi;
    f32x16 st0 = {}, st1 = {};
#pragma unroll
    for (int c = 0; c < 4; c++) {
      bf16x8 kf = *(const bf16x8*)(kp0 + 16 * c);
      st0 = __builtin_amdgcn_mfma_f32_32x32x16_bf16(kf, qf[c], st0, 0, 0, 0);
    }
    if (has1) {
      const unsigned short* kp1 = kp0 + (size_t)32 * D_;
#pragma unroll
      for (int c = 0; c < 4; c++) {
        bf16x8 kf = *(const bf16x8*)(kp1 + 16 * c);
        st1 = __builtin_amdgcn_mfma_f32_32x32x16_bf16(kf, qf[c], st1, 0, 0, 0);
      }
    }

    // ---- scale (+ causal mask on last tile) ----
    if (last) {
#pragma unroll
      for (int r = 0; r < 16; ++r) {
        const int key = kb0 + (r & 3) + 8 * (r >> 2) + 4 * hi;
        st0[r] = (key      <= qrow) ? st0[r] * SC : -1e30f;
        st1[r] = (key + 32 <= qrow) ? st1[r] * SC : -1e30f;
      }
    } else {
#pragma unroll
      for (int r = 0; r < 16; ++r) { st0[r] *= SC; st1[r] *= SC; }
    }

    // ---- online softmax (stats are per-lane scalars) ----
    float tmax = st0[0];
#pragma unroll
    for (int r = 1; r < 16; ++r) tmax = fmaxf(tmax, st0[r]);
#pragma unroll
    for (int r = 0; r < 16; ++r) tmax = fmaxf(tmax, st1[r]);
    tmax = fmaxf(tmax, __shfl_xor(tmax, 32));
    const float mnew  = fmaxf(m, tmax);
    const float alpha = __builtin_amdgcn_exp2f(m - mnew);
    m = mnew;

    float sum = 0.f;
#pragma unroll
    for (int r = 0; r < 16; ++r) { float p = __builtin_amdgcn_exp2f(st0[r] - mnew); st0[r] = p; sum += p; }
#pragma unroll
    for (int r = 0; r < 16; ++r) { float p = __builtin_amdgcn_exp2f(st1[r] - mnew); st1[r] = p; sum += p; }
    sum += __shfl_xor(sum, 32);
    l = l * alpha + sum;

#pragma unroll
    for (int r = 0; r < 16; ++r) { o0[r] *= alpha; o1[r] *= alpha; }

    // ---- pack P^T regs into PV B-fragments (keys stay in-lane) ----
    bf16x8 pf00, pf01, pf10, pf11;
#pragma unroll
    for (int i = 0; i < 8; ++i) {
      pf00[i] = (short)f2bf(st0[i]);     pf01[i] = (short)f2bf(st0[8 + i]);
      pf10[i] = (short)f2bf(st1[i]);     pf11[i] = (short)f2bf(st1[8 + i]);
    }

    // ---- PV: O^T[d][q] += V^T[d][k] * P^T[k][q]; V loaded with the matching
    //      key permutation: slots {0..3,8..11}+4hi per 16-key chunk ----
#pragma unroll
    for (int dh = 0; dh < 2; ++dh) {
      const unsigned short* vrow = vbase + (size_t)(dh * 32 + qi) * T_ + kb0 + 4 * hi;
      f32x16 oc = dh ? o1 : o0;
      oc = __builtin_amdgcn_mfma_f32_32x32x16_bf16(load_v44(vrow),      pf00, oc, 0, 0, 0);
      oc = __builtin_amdgcn_mfma_f32_32x32x16_bf16(load_v44(vrow + 16), pf01, oc, 0, 0, 0);
      if (has1) {
        oc = __builtin_amdgcn_mfma_f32_32x32x16_bf16(load_v44(vrow + 32), pf10, oc, 0, 0, 0);
        oc = __builtin_amdgcn_mfma_f32_32x32x16_bf16(load_v44(vrow + 48), pf11, oc, 0, 0, 0);
      }
      if (dh) o1 = oc; else o0 = oc;
    }
  }

  // ---- normalize + store bf16 (q fixed per lane; d from reg index) ----
  const float inv = 1.0f / l;
  unsigned short* orow = ob + (size_t)(b * T_ + qrow) * (H_ * D_) + h * D_;
#pragma unroll
  for (int dh = 0; dh < 2; ++dh) {
    const f32x16 ov = dh ? o1 : o0;
#pragma unroll
    for (int rg = 0; rg < 4; ++rg) {
      const int d0 = 32 * dh + 8 * rg + 4 * hi;
      ushort4 pk;
      pk.x = f2bf(ov[4 * rg + 0] * inv);
      pk.y = f2bf(ov[4 * rg + 1] * inv);
      pk.z = f2bf(ov[4 * rg + 2] * inv);
      pk.w = f2bf(ov[4 * rg + 3] * inv);
      *(ushort4*)(orow + d0) = pk;
    }
  }
}

// ---------------------------------------------------------------------------
extern "C" void kernel_launch(void* const* d_in, const int* in_sizes, int n_in,
                              void* d_out, int out_size, void* d_ws, size_t ws_size,
                              hipStream_t stream) {
  const float* x    = (const float*)d_in[0];
  const float* cosT = (const float*)d_in[1];
  const float* sinT = (const float*)d_in[2];
  const float* wq   = (const float*)d_in[3];
  const float* wk   = (const float*)d_in[4];
  const float* wv   = (const float*)d_in[5];
  const float* wo   = (const float*)d_in[6];

  float* y    = (float*)d_out;                                  // B*T*C
  float* kout = (float*)d_out + (size_t)B_ * T_ * C_;           // B*Hk*T*D
  float* vout = kout + (size_t)B_ * HK_ * T_ * D_;

  // Workspace layout (peak 56,623,104 B; reuses are stream-ordered):
  //   [0,        16M)  x_bf   -> (after GEMM1) q_bf
  //   [16M,      26M)  wqkv   -> (after GEMM1) k_bf, v_t
  //   [26M,      46M)  qkv_bf -> (after rope)  o_bf
  //   [46M,      54M)  wo_bf
  char* ws = (char*)d_ws;
  unsigned short* x_bf   = (unsigned short*)(ws);               // 16,777,216 B
  unsigned short* q_bf   = x_bf;                                // reuse after GEMM1
  unsigned short* wqkv   = (unsigned short*)(ws + 16777216);    // 10,485,760 B
  unsigned short* k_bf   = wqkv;                                //  2,097,152 B (reuse)
  unsigned short* v_t    = (unsigned short*)(ws + 18874368);    //  2,097,152 B (reuse)
  unsigned short* qkv_bf = (unsigned short*)(ws + 27262976);    // 20,971,520 B
  unsigned short* o_bf   = qkv_bf;                              // reuse after rope
  unsigned short* wo_bf  = (unsigned short*)(ws + 48234496);    //  8,388,608 B -> end 56,623,104

  const int M = B_ * T_;  // 4096

  f32_to_bf16<<<8192, 256, 0, stream>>>(x,  x_bf, 2097152);
  f32_to_bf16<<<4096, 256, 0, stream>>>(wq, wqkv,                 1048576);
  f32_to_bf16<<<512,  256, 0, stream>>>(wk, wqkv + 2048 * 2048,   131072);
  f32_to_bf16<<<512,  256, 0, stream>>>(wv, wqkv + 2304 * 2048,   131072);

  gemm_bf16<true><<<dim3(2560 / 128, M / 128), 256, 0, stream>>>(x_bf, wqkv, qkv_bf, M, 2560, C_);

  gqa_rope_q<<<16384, 256, 0, stream>>>(qkv_bf, cosT, sinT, q_bf);
  gqa_rope_k<<<2048,  256, 0, stream>>>(qkv_bf, cosT, sinT, kout, k_bf);
  gqa_v_reorder<<<4096, 256, 0, stream>>>(qkv_bf, vout, v_t);

  f32_to_bf16<<<4096, 256, 0, stream>>>(wo, wo_bf, 1048576);

  gqa_attn2<<<512, 512, 0, stream>>>(q_bf, k_bf, v_t, o_bf);

  gemm_bf16<false><<<dim3(C_ / 128, M / 128), 256, 0, stream>>>(o_bf, wo_bf, y, M, C_, H_ * D_);
}

// Round 4
// 235.024 us; speedup vs baseline: 3.3761x; 1.5031x over previous
//
#include <hip/hip_runtime.h>
#include <hip/hip_bf16.h>

#define B_ 2
#define T_ 2048
#define C_ 2048
#define H_ 32
#define HK_ 4
#define D_ 64

typedef __attribute__((ext_vector_type(4)))  float f32x4;
typedef __attribute__((ext_vector_type(2)))  float f32x2;
typedef __attribute__((ext_vector_type(16))) float f32x16;
typedef __attribute__((ext_vector_type(8)))  short bf16x8;

static __device__ __forceinline__ unsigned short f2bf(float f) {
  union { __hip_bfloat16 h; unsigned short s; } u;
  u.h = __float2bfloat16(f);
  return u.s;
}
static __device__ __forceinline__ float bf2f(unsigned short s) {
  union { unsigned int u; float f; } u; u.u = ((unsigned int)s) << 16; return u.f;
}

#define GLD16(gp, lp) __builtin_amdgcn_global_load_lds( \
    (const __attribute__((address_space(1))) unsigned int*)(gp), \
    (__attribute__((address_space(3))) unsigned int*)(unsigned int)(uintptr_t)(lp), 16, 0, 0)

// ---------------------------------------------------------------------------
// f32 -> bf16 convert (vectorized)
// ---------------------------------------------------------------------------
__global__ void f32_to_bf16(const float* __restrict__ src, unsigned short* __restrict__ dst, int n4) {
  const int i = blockIdx.x * blockDim.x + threadIdx.x;
  if (i >= n4) return;
  f32x4 v = *(const f32x4*)(src + 4 * (size_t)i);
  ushort4 o;
  o.x = f2bf(v[0]); o.y = f2bf(v[1]); o.z = f2bf(v[2]); o.w = f2bf(v[3]);
  *(ushort4*)(dst + 4 * (size_t)i) = o;
}

// ---------------------------------------------------------------------------
// GEMM: C[M,N] = A[M,K]_bf16 * W[N,K]_bf16^T, m97-style: 128x128 tile, BK=32,
// global_load_lds width 16, linear [128][32] LDS (conflict-free frag reads).
// ---------------------------------------------------------------------------
template<bool BF16OUT>
__global__ __launch_bounds__(256)
void gemm_bf16(const unsigned short* __restrict__ A, const unsigned short* __restrict__ W,
               void* __restrict__ Cout, int M, int N, int K) {
  __shared__ unsigned short As[128 * 32];
  __shared__ unsigned short Ws[128 * 32];

  const int tid  = threadIdx.x;
  const int lane = tid & 63;
  const int w    = tid >> 6;
  const int wm   = w >> 1, wn = w & 1;
  const int g    = lane >> 4;
  const int lr   = lane & 15;

  const int bm = blockIdx.y * 128;
  const int bn = blockIdx.x * 128;

  const int srow = lane >> 2;        // 0..15
  const int scol = (lane & 3) * 8;   // 0,8,16,24
  const unsigned short* Ag = A + (size_t)(bm + 16 * w + srow) * K + scol;
  const unsigned short* Wg = W + (size_t)(bn + 16 * w + srow) * K + scol;
  unsigned short* Asl0 = &As[(16 * w) * 32];
  unsigned short* Asl1 = &As[(64 + 16 * w) * 32];
  unsigned short* Wsl0 = &Ws[(16 * w) * 32];
  unsigned short* Wsl1 = &Ws[(64 + 16 * w) * 32];

  f32x4 acc[4][4] = {};

  for (int k0 = 0; k0 < K; k0 += 32) {
    __syncthreads();
    GLD16(Ag + k0,                    Asl0);
    GLD16(Ag + (size_t)64 * K + k0,   Asl1);
    GLD16(Wg + k0,                    Wsl0);
    GLD16(Wg + (size_t)64 * K + k0,   Wsl1);
    __syncthreads();

    bf16x8 af[4], wf[4];
#pragma unroll
    for (int m = 0; m < 4; m++)
      af[m] = *(const bf16x8*)&As[(wm * 64 + m * 16 + lr) * 32 + g * 8];
#pragma unroll
    for (int n = 0; n < 4; n++)
      wf[n] = *(const bf16x8*)&Ws[(wn * 64 + n * 16 + lr) * 32 + g * 8];
#pragma unroll
    for (int m = 0; m < 4; m++)
#pragma unroll
      for (int n = 0; n < 4; n++)
        acc[m][n] = __builtin_amdgcn_mfma_f32_16x16x32_bf16(af[m], wf[n], acc[m][n], 0, 0, 0);
  }

  // C/D layout: col = lane&15, row = 4*(lane>>4) + reg
#pragma unroll
  for (int m = 0; m < 4; m++) {
    const int row = bm + wm * 64 + m * 16 + g * 4;
#pragma unroll
    for (int n = 0; n < 4; n++) {
      const int col = bn + wn * 64 + n * 16 + lr;
#pragma unroll
      for (int r = 0; r < 4; r++) {
        if (BF16OUT)
          ((unsigned short*)Cout)[(size_t)(row + r) * N + col] = f2bf(acc[m][n][r]);
        else
          ((float*)Cout)[(size_t)(row + r) * N + col] = acc[m][n][r];
      }
    }
  }
}

// ---------------------------------------------------------------------------
// RoPE q: qkv_bf (B*T, 2560) cols [0,2048) -> q_bf (B,H,T,D) bf16
// ---------------------------------------------------------------------------
__global__ void gqa_rope_q(const unsigned short* __restrict__ qkv,
                           const float* __restrict__ cosT,
                           const float* __restrict__ sinT,
                           unsigned short* __restrict__ qb) {
  const int idx = blockIdx.x * blockDim.x + threadIdx.x; // B*T*H*32
  const int i  = idx & 31;
  const int h  = (idx >> 5) & 31;
  const int bt = idx >> 10;
  const int t  = bt & (T_ - 1);
  const int b  = bt >> 11;

  const unsigned int qv = *(const unsigned int*)(qkv + (size_t)bt * 2560 + h * D_ + 2 * i);
  const float x1 = bf2f((unsigned short)(qv & 0xffff));
  const float x2 = bf2f((unsigned short)(qv >> 16));
  const float c = cosT[t * D_ + 2 * i];
  const float s = sinT[t * D_ + 2 * i];
  const float o0 = x1 * c - x2 * s;
  const float o1 = x2 * c + x1 * s;
  const size_t o = ((size_t)(b * H_ + h) * T_ + t) * D_ + 2 * i;
  *(unsigned int*)(qb + o) = (unsigned int)f2bf(o0) | ((unsigned int)f2bf(o1) << 16);
}

// ---------------------------------------------------------------------------
// RoPE k: qkv_bf cols [2048,2304) -> kout f32 (B,Hk,T,D) + k_bf bf16 same
// ---------------------------------------------------------------------------
__global__ void gqa_rope_k(const unsigned short* __restrict__ qkv,
                           const float* __restrict__ cosT,
                           const float* __restrict__ sinT,
                           float* __restrict__ kout,
                           unsigned short* __restrict__ kb) {
  const int idx = blockIdx.x * blockDim.x + threadIdx.x; // B*T*Hk*32
  const int i  = idx & 31;
  const int hk = (idx >> 5) & 3;
  const int bt = idx >> 7;
  const int t  = bt & (T_ - 1);
  const int b  = bt >> 11;

  const unsigned int kv = *(const unsigned int*)(qkv + (size_t)bt * 2560 + 2048 + hk * D_ + 2 * i);
  const float x1 = bf2f((unsigned short)(kv & 0xffff));
  const float x2 = bf2f((unsigned short)(kv >> 16));
  const float c = cosT[t * D_ + 2 * i];
  const float s = sinT[t * D_ + 2 * i];
  const float o0 = x1 * c - x2 * s;
  const float o1 = x2 * c + x1 * s;
  const size_t o = ((size_t)(b * HK_ + hk) * T_ + t) * D_ + 2 * i;
  f32x2 ov; ov[0] = o0; ov[1] = o1;
  *(f32x2*)(kout + o) = ov;
  *(unsigned int*)(kb + o) = (unsigned int)f2bf(o0) | ((unsigned int)f2bf(o1) << 16);
}

// ---------------------------------------------------------------------------
// v: qkv_bf cols [2304,2560) -> vout f32 (B,Hk,T,D) + vT bf16 (B,Hk,D,T)
// ---------------------------------------------------------------------------
__global__ void gqa_v_reorder(const unsigned short* __restrict__ qkv,
                              float* __restrict__ vout,
                              unsigned short* __restrict__ vt) {
  const int idx = blockIdx.x * blockDim.x + threadIdx.x; // B*T*Hk*D = 1048576
  const int d  = idx & 63;
  const int hk = (idx >> 6) & 3;
  const int bt = idx >> 8;
  const int t  = bt & (T_ - 1);
  const int b  = bt >> 11;

  const unsigned short v = qkv[(size_t)bt * 2560 + 2304 + hk * D_ + d];
  vout[((size_t)(b * HK_ + hk) * T_ + t) * D_ + d] = bf2f(v);
  vt[((size_t)(b * HK_ + hk) * D_ + d) * T_ + t] = v;
}

// ---------------------------------------------------------------------------
// Flash attention v3: 8 waves/block share one (b,hk) KV group; K and V^T tiles
// (64 keys) staged in double-buffered LDS via global_load_lds with XOR swizzle
// (pre-swizzled global source, swizzled LDS reads). Swapped QK^T (32x32 MFMA,
// stats per-lane scalars); PV from register P^T; counted vmcnt prefetch.
// ---------------------------------------------------------------------------
__global__ __launch_bounds__(512)
void gqa_attn3(const unsigned short* __restrict__ qb,
               const unsigned short* __restrict__ kb,
               const unsigned short* __restrict__ vt,
               unsigned short* __restrict__ ob) {
  __shared__ unsigned short Ks[2][4096];   // [64 keys][64 d], 16B-chunk XOR-swizzled
  __shared__ unsigned short Vs[2][4096];   // [64 d][64 keys], same swizzle

  const int tid  = threadIdx.x;
  const int lane = tid & 63;
  const int w    = tid >> 6;      // 0..7
  const int qi   = lane & 31;
  const int hi   = lane >> 5;

  const int qt = 63 - (int)(blockIdx.x >> 3);   // heavy q-tiles first
  const int go = blockIdx.x & 7;                // (b,hk) octet
  const int b  = go >> 2;
  const int hk = go & 3;
  const int h  = hk * 8 + w;                    // each wave: one head of the group
  const int bh = b * H_ + h;

  const int qbase = qt * 32;
  const int qrow  = qbase + qi;

  // Q fragment (B operand): row q, d = 16c + 8hi + i
  const unsigned short* qptr = qb + ((size_t)bh * T_ + qrow) * D_ + 8 * hi;
  bf16x8 qf[4];
#pragma unroll
  for (int c = 0; c < 4; c++) qf[c] = *(const bf16x8*)(qptr + 16 * c);

  const unsigned short* kvK = kb + (size_t)(b * HK_ + hk) * T_ * D_;
  const unsigned short* kvV = vt + (size_t)(b * HK_ + hk) * D_ * T_;

  // staging: thread -> (row = 8w + lane>>3, chunk16 = lane&7); source chunk
  // pre-XOR'd so LDS reads use chunk' = chunk ^ (row&7) (rule both-sides).
  const int srow   = lane >> 3;                 // 0..7  (= row&7)
  const int schunk = (lane & 7) ^ srow;         // pre-swizzled 16B chunk
  const int krow   = 8 * w + srow;              // key row (K) / d row (V)
  unsigned short* ldsK0 = &Ks[0][w * 512];
  unsigned short* ldsK1 = &Ks[1][w * 512];
  unsigned short* ldsV0 = &Vs[0][w * 512];
  unsigned short* ldsV1 = &Vs[1][w * 512];

#define STAGE_KV(pp, kk0) do { \
    GLD16(kvK + (size_t)((kk0) + krow) * D_ + schunk * 8, (pp) ? ldsK1 : ldsK0); \
    GLD16(kvV + (size_t)krow * T_ + (kk0) + schunk * 8,   (pp) ? ldsV1 : ldsV0); \
  } while (0)

  f32x16 o0 = {}, o1 = {};           // O^T: col q = lane&31; rows d
  float m = -1e30f, l = 0.f;
  const float SC = 0.125f * 1.44269504089f;  // 1/sqrt(D) * log2(e)
  const int swz = qi & 7;

  const int ntiles = ((qbase + 31) >> 6) + 1;
  int p = 0;
  STAGE_KV(0, 0);

  for (int it = 0; it < ntiles; ++it) {
    const int kb0 = it * 64;
    const bool last = (it == ntiles - 1);
    const bool has1 = (kb0 + 32 <= qbase + 31);

    if (it + 1 < ntiles) {
      STAGE_KV(p ^ 1, kb0 + 64);
      asm volatile("s_waitcnt vmcnt(2)" ::: "memory");   // tile-it DMA done, prefetch in flight
    } else {
      asm volatile("s_waitcnt vmcnt(0)" ::: "memory");
    }
    asm volatile("s_barrier" ::: "memory");

    const unsigned short* Kt = &Ks[p][0];
    const unsigned short* Vt = &Vs[p][0];

    // ---- QK^T swapped: S^T[key][q], A = K rows (from LDS), B = Q rows ----
    f32x16 st0 = {}, st1 = {};
#pragma unroll
    for (int c = 0; c < 4; c++) {
      bf16x8 kf = *(const bf16x8*)&Kt[qi * 64 + (((hi + 2 * c) ^ swz) << 3)];
      st0 = __builtin_amdgcn_mfma_f32_32x32x16_bf16(kf, qf[c], st0, 0, 0, 0);
    }
    if (has1) {
#pragma unroll
      for (int c = 0; c < 4; c++) {
        bf16x8 kf = *(const bf16x8*)&Kt[(32 + qi) * 64 + (((hi + 2 * c) ^ swz) << 3)];
        st1 = __builtin_amdgcn_mfma_f32_32x32x16_bf16(kf, qf[c], st1, 0, 0, 0);
      }
    }

    // ---- scale (+ causal mask on last tile) ----
    if (last) {
#pragma unroll
      for (int r = 0; r < 16; ++r) {
        const int key = kb0 + (r & 3) + 8 * (r >> 2) + 4 * hi;
        st0[r] = (key      <= qrow) ? st0[r] * SC : -1e30f;
        st1[r] = (key + 32 <= qrow) ? st1[r] * SC : -1e30f;
      }
    } else {
#pragma unroll
      for (int r = 0; r < 16; ++r) { st0[r] *= SC; st1[r] *= SC; }
    }

    // ---- online softmax (stats are per-lane scalars) ----
    float tmax = st0[0];
#pragma unroll
    for (int r = 1; r < 16; ++r) tmax = fmaxf(tmax, st0[r]);
    if (has1) {
#pragma unroll
      for (int r = 0; r < 16; ++r) tmax = fmaxf(tmax, st1[r]);
    }
    tmax = fmaxf(tmax, __shfl_xor(tmax, 32));
    const float mnew  = fmaxf(m, tmax);
    const float alpha = __builtin_amdgcn_exp2f(m - mnew);
    m = mnew;

    float sum = 0.f;
#pragma unroll
    for (int r = 0; r < 16; ++r) { float pv = __builtin_amdgcn_exp2f(st0[r] - mnew); st0[r] = pv; sum += pv; }
    if (has1) {
#pragma unroll
      for (int r = 0; r < 16; ++r) { float pv = __builtin_amdgcn_exp2f(st1[r] - mnew); st1[r] = pv; sum += pv; }
    }
    sum += __shfl_xor(sum, 32);
    l = l * alpha + sum;

#pragma unroll
    for (int r = 0; r < 16; ++r) { o0[r] *= alpha; o1[r] *= alpha; }

    // ---- pack P^T regs into PV B-fragments (keys stay in-lane) ----
    bf16x8 pf[4];
#pragma unroll
    for (int i = 0; i < 8; ++i) {
      pf[0][i] = (short)f2bf(st0[i]);     pf[1][i] = (short)f2bf(st0[8 + i]);
      pf[2][i] = (short)f2bf(st1[i]);     pf[3][i] = (short)f2bf(st1[8 + i]);
    }

    // ---- PV: O^T[d][q] += V^T[d][k] * P^T[k][q]; V chunks from swizzled LDS,
    //      key slots {0..3,8..11}+4hi per 16-key chunk ----
#pragma unroll
    for (int dh = 0; dh < 2; ++dh) {
      const unsigned short* Vrow = &Vt[(dh * 32 + qi) * 64];
      f32x16 oc = dh ? o1 : o0;
#pragma unroll
      for (int c = 0; c < 4; ++c) {
        if (c >= 2 && !has1) break;
        short4 a = *(const short4*)&Vrow[(((2 * c)     ^ swz) << 3) + 4 * hi];
        short4 e = *(const short4*)&Vrow[(((2 * c + 1) ^ swz) << 3) + 4 * hi];
        bf16x8 vf;
        vf[0] = a.x; vf[1] = a.y; vf[2] = a.z; vf[3] = a.w;
        vf[4] = e.x; vf[5] = e.y; vf[6] = e.z; vf[7] = e.w;
        oc = __builtin_amdgcn_mfma_f32_32x32x16_bf16(vf, pf[c], oc, 0, 0, 0);
      }
      if (dh) o1 = oc; else o0 = oc;
    }

    asm volatile("s_waitcnt lgkmcnt(0)" ::: "memory");
    asm volatile("s_barrier" ::: "memory");   // all waves done reading buf p
    p ^= 1;
  }

  // ---- normalize + store bf16 (q fixed per lane; d from reg index) ----
  const float inv = 1.0f / l;
  unsigned short* orow = ob + (size_t)(b * T_ + qrow) * (H_ * D_) + h * D_;
#pragma unroll
  for (int dh = 0; dh < 2; ++dh) {
    const f32x16 ov = dh ? o1 : o0;
#pragma unroll
    for (int rg = 0; rg < 4; ++rg) {
      const int d0 = 32 * dh + 8 * rg + 4 * hi;
      ushort4 pk;
      pk.x = f2bf(ov[4 * rg + 0] * inv);
      pk.y = f2bf(ov[4 * rg + 1] * inv);
      pk.z = f2bf(ov[4 * rg + 2] * inv);
      pk.w = f2bf(ov[4 * rg + 3] * inv);
      *(ushort4*)(orow + d0) = pk;
    }
  }
#undef STAGE_KV
}

// ---------------------------------------------------------------------------
extern "C" void kernel_launch(void* const* d_in, const int* in_sizes, int n_in,
                              void* d_out, int out_size, void* d_ws, size_t ws_size,
                              hipStream_t stream) {
  const float* x    = (const float*)d_in[0];
  const float* cosT = (const float*)d_in[1];
  const float* sinT = (const float*)d_in[2];
  const float* wq   = (const float*)d_in[3];
  const float* wk   = (const float*)d_in[4];
  const float* wv   = (const float*)d_in[5];
  const float* wo   = (const float*)d_in[6];

  float* y    = (float*)d_out;                                  // B*T*C
  float* kout = (float*)d_out + (size_t)B_ * T_ * C_;           // B*Hk*T*D
  float* vout = kout + (size_t)B_ * HK_ * T_ * D_;

  // Workspace layout (peak 56,623,104 B; reuses are stream-ordered):
  char* ws = (char*)d_ws;
  unsigned short* x_bf   = (unsigned short*)(ws);               // 16,777,216 B
  unsigned short* q_bf   = x_bf;                                // reuse after GEMM1
  unsigned short* wqkv   = (unsigned short*)(ws + 16777216);    // 10,485,760 B
  unsigned short* k_bf   = wqkv;                                //  2,097,152 B (reuse)
  unsigned short* v_t    = (unsigned short*)(ws + 18874368);    //  2,097,152 B (reuse)
  unsigned short* qkv_bf = (unsigned short*)(ws + 27262976);    // 20,971,520 B
  unsigned short* o_bf   = qkv_bf;                              // reuse after rope
  unsigned short* wo_bf  = (unsigned short*)(ws + 48234496);    //  8,388,608 B -> end 56,623,104

  const int M = B_ * T_;  // 4096

  f32_to_bf16<<<8192, 256, 0, stream>>>(x,  x_bf, 2097152);
  f32_to_bf16<<<4096, 256, 0, stream>>>(wq, wqkv,                 1048576);
  f32_to_bf16<<<512,  256, 0, stream>>>(wk, wqkv + 2048 * 2048,   131072);
  f32_to_bf16<<<512,  256, 0, stream>>>(wv, wqkv + 2304 * 2048,   131072);

  gemm_bf16<true><<<dim3(2560 / 128, M / 128), 256, 0, stream>>>(x_bf, wqkv, qkv_bf, M, 2560, C_);

  gqa_rope_q<<<16384, 256, 0, stream>>>(qkv_bf, cosT, sinT, q_bf);
  gqa_rope_k<<<2048,  256, 0, stream>>>(qkv_bf, cosT, sinT, kout, k_bf);
  gqa_v_reorder<<<4096, 256, 0, stream>>>(qkv_bf, vout, v_t);

  f32_to_bf16<<<4096, 256, 0, stream>>>(wo, wo_bf, 1048576);

  gqa_attn3<<<512, 512, 0, stream>>>(q_bf, k_bf, v_t, o_bf);

  gemm_bf16<false><<<dim3(C_ / 128, M / 128), 256, 0, stream>>>(o_bf, wo_bf, y, M, C_, H_ * D_);
}

// Round 5
// 226.797 us; speedup vs baseline: 3.4985x; 1.0363x over previous
//
#include <hip/hip_runtime.h>
#include <hip/hip_bf16.h>

#define B_ 2
#define T_ 2048
#define C_ 2048
#define H_ 32
#define HK_ 4
#define D_ 64

typedef __attribute__((ext_vector_type(4)))  float f32x4;
typedef __attribute__((ext_vector_type(2)))  float f32x2;
typedef __attribute__((ext_vector_type(16))) float f32x16;
typedef __attribute__((ext_vector_type(8)))  short bf16x8;

static __device__ __forceinline__ unsigned short f2bf(float f) {
  union { __hip_bfloat16 h; unsigned short s; } u;
  u.h = __float2bfloat16(f);
  return u.s;
}
static __device__ __forceinline__ float bf2f(unsigned short s) {
  union { unsigned int u; float f; } u; u.u = ((unsigned int)s) << 16; return u.f;
}
// packed f32 pair -> 2 bf16 (RNE) in one instruction
static __device__ __forceinline__ unsigned int cvtpk(float lo, float hi) {
  unsigned int r;
  asm("v_cvt_pk_bf16_f32 %0, %1, %2" : "=v"(r) : "v"(lo), "v"(hi));
  return r;
}

#define GLD16(gp, lp) __builtin_amdgcn_global_load_lds( \
    (const __attribute__((address_space(1))) unsigned int*)(gp), \
    (__attribute__((address_space(3))) unsigned int*)(unsigned int)(uintptr_t)(lp), 16, 0, 0)

// ---------------------------------------------------------------------------
// f32 -> bf16 convert (vectorized)
// ---------------------------------------------------------------------------
__global__ void f32_to_bf16(const float* __restrict__ src, unsigned short* __restrict__ dst, int n4) {
  const int i = blockIdx.x * blockDim.x + threadIdx.x;
  if (i >= n4) return;
  f32x4 v = *(const f32x4*)(src + 4 * (size_t)i);
  ushort4 o;
  o.x = f2bf(v[0]); o.y = f2bf(v[1]); o.z = f2bf(v[2]); o.w = f2bf(v[3]);
  *(ushort4*)(dst + 4 * (size_t)i) = o;
}

// ---------------------------------------------------------------------------
// GEMM: C[M,N] = A[M,K]_bf16 * W[N,K]_bf16^T (m97 structure, unchanged)
// ---------------------------------------------------------------------------
template<bool BF16OUT>
__global__ __launch_bounds__(256)
void gemm_bf16(const unsigned short* __restrict__ A, const unsigned short* __restrict__ W,
               void* __restrict__ Cout, int M, int N, int K) {
  __shared__ unsigned short As[128 * 32];
  __shared__ unsigned short Ws[128 * 32];

  const int tid  = threadIdx.x;
  const int lane = tid & 63;
  const int w    = tid >> 6;
  const int wm   = w >> 1, wn = w & 1;
  const int g    = lane >> 4;
  const int lr   = lane & 15;

  const int bm = blockIdx.y * 128;
  const int bn = blockIdx.x * 128;

  const int srow = lane >> 2;        // 0..15
  const int scol = (lane & 3) * 8;   // 0,8,16,24
  const unsigned short* Ag = A + (size_t)(bm + 16 * w + srow) * K + scol;
  const unsigned short* Wg = W + (size_t)(bn + 16 * w + srow) * K + scol;
  unsigned short* Asl0 = &As[(16 * w) * 32];
  unsigned short* Asl1 = &As[(64 + 16 * w) * 32];
  unsigned short* Wsl0 = &Ws[(16 * w) * 32];
  unsigned short* Wsl1 = &Ws[(64 + 16 * w) * 32];

  f32x4 acc[4][4] = {};

  for (int k0 = 0; k0 < K; k0 += 32) {
    __syncthreads();
    GLD16(Ag + k0,                    Asl0);
    GLD16(Ag + (size_t)64 * K + k0,   Asl1);
    GLD16(Wg + k0,                    Wsl0);
    GLD16(Wg + (size_t)64 * K + k0,   Wsl1);
    __syncthreads();

    bf16x8 af[4], wf[4];
#pragma unroll
    for (int m = 0; m < 4; m++)
      af[m] = *(const bf16x8*)&As[(wm * 64 + m * 16 + lr) * 32 + g * 8];
#pragma unroll
    for (int n = 0; n < 4; n++)
      wf[n] = *(const bf16x8*)&Ws[(wn * 64 + n * 16 + lr) * 32 + g * 8];
#pragma unroll
    for (int m = 0; m < 4; m++)
#pragma unroll
      for (int n = 0; n < 4; n++)
        acc[m][n] = __builtin_amdgcn_mfma_f32_16x16x32_bf16(af[m], wf[n], acc[m][n], 0, 0, 0);
  }

  // C/D layout: col = lane&15, row = 4*(lane>>4) + reg
#pragma unroll
  for (int m = 0; m < 4; m++) {
    const int row = bm + wm * 64 + m * 16 + g * 4;
#pragma unroll
    for (int n = 0; n < 4; n++) {
      const int col = bn + wn * 64 + n * 16 + lr;
#pragma unroll
      for (int r = 0; r < 4; r++) {
        if (BF16OUT)
          ((unsigned short*)Cout)[(size_t)(row + r) * N + col] = f2bf(acc[m][n][r]);
        else
          ((float*)Cout)[(size_t)(row + r) * N + col] = acc[m][n][r];
      }
    }
  }
}

// ---------------------------------------------------------------------------
// RoPE q: qkv_bf (B*T, 2560) cols [0,2048) -> q_bf (B,H,T,D) bf16
// ---------------------------------------------------------------------------
__global__ void gqa_rope_q(const unsigned short* __restrict__ qkv,
                           const float* __restrict__ cosT,
                           const float* __restrict__ sinT,
                           unsigned short* __restrict__ qb) {
  const int idx = blockIdx.x * blockDim.x + threadIdx.x; // B*T*H*32
  const int i  = idx & 31;
  const int h  = (idx >> 5) & 31;
  const int bt = idx >> 10;
  const int t  = bt & (T_ - 1);
  const int b  = bt >> 11;

  const unsigned int qv = *(const unsigned int*)(qkv + (size_t)bt * 2560 + h * D_ + 2 * i);
  const float x1 = bf2f((unsigned short)(qv & 0xffff));
  const float x2 = bf2f((unsigned short)(qv >> 16));
  const float c = cosT[t * D_ + 2 * i];
  const float s = sinT[t * D_ + 2 * i];
  const float o0 = x1 * c - x2 * s;
  const float o1 = x2 * c + x1 * s;
  const size_t o = ((size_t)(b * H_ + h) * T_ + t) * D_ + 2 * i;
  *(unsigned int*)(qb + o) = (unsigned int)f2bf(o0) | ((unsigned int)f2bf(o1) << 16);
}

// ---------------------------------------------------------------------------
// RoPE k: qkv_bf cols [2048,2304) -> kout f32 (B,Hk,T,D) + k_bf bf16 same
// ---------------------------------------------------------------------------
__global__ void gqa_rope_k(const unsigned short* __restrict__ qkv,
                           const float* __restrict__ cosT,
                           const float* __restrict__ sinT,
                           float* __restrict__ kout,
                           unsigned short* __restrict__ kb) {
  const int idx = blockIdx.x * blockDim.x + threadIdx.x; // B*T*Hk*32
  const int i  = idx & 31;
  const int hk = (idx >> 5) & 3;
  const int bt = idx >> 7;
  const int t  = bt & (T_ - 1);
  const int b  = bt >> 11;

  const unsigned int kv = *(const unsigned int*)(qkv + (size_t)bt * 2560 + 2048 + hk * D_ + 2 * i);
  const float x1 = bf2f((unsigned short)(kv & 0xffff));
  const float x2 = bf2f((unsigned short)(kv >> 16));
  const float c = cosT[t * D_ + 2 * i];
  const float s = sinT[t * D_ + 2 * i];
  const float o0 = x1 * c - x2 * s;
  const float o1 = x2 * c + x1 * s;
  const size_t o = ((size_t)(b * HK_ + hk) * T_ + t) * D_ + 2 * i;
  f32x2 ov; ov[0] = o0; ov[1] = o1;
  *(f32x2*)(kout + o) = ov;
  *(unsigned int*)(kb + o) = (unsigned int)f2bf(o0) | ((unsigned int)f2bf(o1) << 16);
}

// ---------------------------------------------------------------------------
// v: qkv_bf cols [2304,2560) -> vout f32 (B,Hk,T,D) + vT bf16 (B,Hk,D,T)
// vT key-dim is stored in MFMA-slot order per 16-key group:
//   key (i&3)+8*(i>>2)+4*h  ->  position i + 8*h   (so PV B-frag = one b128)
// ---------------------------------------------------------------------------
__global__ void gqa_v_reorder(const unsigned short* __restrict__ qkv,
                              float* __restrict__ vout,
                              unsigned short* __restrict__ vt) {
  const int idx = blockIdx.x * blockDim.x + threadIdx.x; // B*T*Hk*D = 1048576
  const int d  = idx & 63;
  const int hk = (idx >> 6) & 3;
  const int bt = idx >> 8;
  const int t  = bt & (T_ - 1);
  const int b  = bt >> 11;

  const unsigned short v = qkv[(size_t)bt * 2560 + 2304 + hk * D_ + d];
  vout[((size_t)(b * HK_ + hk) * T_ + t) * D_ + d] = bf2f(v);

  const int tm   = t & 15;
  const int tpos = (t & ~15) | ((tm & 3) + ((tm >> 3) << 2) + ((tm & 4) << 1));
  vt[((size_t)(b * HK_ + hk) * D_ + d) * T_ + tpos] = v;
}

// ---------------------------------------------------------------------------
// Flash attention v4: 8 waves/block share one (b,hk) KV; triple-buffered LDS
// (one barrier/tile, counted vmcnt), swapped QK^T (stats per-lane), slot-
// ordered V (PV frag = single b128), SC folded into exp, cvt_pk P-pack,
// defer-max rescale, setprio around MFMA clusters.
// ---------------------------------------------------------------------------
__global__ __launch_bounds__(512, 4)
void gqa_attn4(const unsigned short* __restrict__ qb,
               const unsigned short* __restrict__ kb,
               const unsigned short* __restrict__ vt,
               unsigned short* __restrict__ ob) {
  __shared__ unsigned short Ks[3][4096];   // [64 keys][64 d], 16B-chunk XOR-swizzled
  __shared__ unsigned short Vs[3][4096];   // [64 d][64 key-slots], same swizzle

  const int tid  = threadIdx.x;
  const int lane = tid & 63;
  const int w    = tid >> 6;      // 0..7
  const int qi   = lane & 31;
  const int hi   = lane >> 5;

  const int qt = 63 - (int)(blockIdx.x >> 3);   // heavy q-tiles first
  const int go = blockIdx.x & 7;                // (b,hk) octet
  const int b  = go >> 2;
  const int hk = go & 3;
  const int h  = hk * 8 + w;
  const int bh = b * H_ + h;

  const int qbase = qt * 32;
  const int qrow  = qbase + qi;

  // Q fragment (B operand): row q, d = 16c + 8hi + i
  const unsigned short* qptr = qb + ((size_t)bh * T_ + qrow) * D_ + 8 * hi;
  bf16x8 qf[4];
#pragma unroll
  for (int c = 0; c < 4; c++) qf[c] = *(const bf16x8*)(qptr + 16 * c);

  // staging: thread -> (row = 8w + lane>>3, chunk = (lane&7) ^ (row&7))
  const int srow   = lane >> 3;
  const int schunk = (lane & 7) ^ srow;
  const int krow   = 8 * w + srow;
  const unsigned short* gK = kb + (size_t)(b * HK_ + hk) * T_ * D_ + (size_t)krow * D_ + schunk * 8;
  const unsigned short* gV = vt + (size_t)(b * HK_ + hk) * D_ * T_ + (size_t)krow * T_ + schunk * 8;
  unsigned short* ldsK = &Ks[0][w * 512];
  unsigned short* ldsV = &Vs[0][w * 512];

#define STAGE_KV(pp, kk0) do { \
    GLD16(gK + (size_t)(kk0) * D_, ldsK + (pp) * 4096); \
    GLD16(gV + (kk0),              ldsV + (pp) * 4096); \
  } while (0)

  f32x16 o0 = {}, o1 = {};           // O^T: col q = lane&31; rows d
  float m = -1e30f, l = 0.f;
  float c1 = 0.f;                    // -m*SC (valid after first tile)
  const float SC   = 0.125f * 1.44269504089f;  // 1/sqrt(D) * log2(e)
  const float THRR = 44.3614195f;              // 8 / SC (defer-max threshold, raw units)
  const int   swz  = qi & 7;

  const int nt = ((qbase + 31) >> 6) + 1;
  STAGE_KV(0, 0);
  if (nt > 1) STAGE_KV(1, 64);

  int p = 0;
  for (int it = 0; it < nt; ++it) {
    const int kb0 = it * 64;
    const bool last = (it == nt - 1);
    const bool has1 = (kb0 + 32 <= qbase + 31);

    asm volatile("s_waitcnt lgkmcnt(0)" ::: "memory");
    if (it + 1 < nt) asm volatile("s_waitcnt vmcnt(2)" ::: "memory");
    else             asm volatile("s_waitcnt vmcnt(0)" ::: "memory");
    asm volatile("s_barrier" ::: "memory");
    if (it + 2 < nt) STAGE_KV((p + 2 > 2) ? p - 1 : p + 2, kb0 + 128);

    const unsigned short* Kt = &Ks[0][0] + p * 4096;
    const unsigned short* Vt = &Vs[0][0] + p * 4096;

    // ---- QK^T swapped: S^T[key][q], A = K rows (LDS), B = Q rows ----
    f32x16 st0 = {}, st1 = {};
    __builtin_amdgcn_s_setprio(1);
#pragma unroll
    for (int c = 0; c < 4; c++) {
      bf16x8 kf = *(const bf16x8*)&Kt[qi * 64 + (((hi + 2 * c) ^ swz) << 3)];
      st0 = __builtin_amdgcn_mfma_f32_32x32x16_bf16(kf, qf[c], st0, 0, 0, 0);
    }
    if (!last || has1) {
#pragma unroll
      for (int c = 0; c < 4; c++) {
        bf16x8 kf = *(const bf16x8*)&Kt[(32 + qi) * 64 + (((hi + 2 * c) ^ swz) << 3)];
        st1 = __builtin_amdgcn_mfma_f32_32x32x16_bf16(kf, qf[c], st1, 0, 0, 0);
      }
    }
    __builtin_amdgcn_s_setprio(0);

    // ---- causal mask on last tile (raw units) ----
    if (last) {
#pragma unroll
      for (int r = 0; r < 16; ++r) {
        const int key = kb0 + (r & 3) + 8 * (r >> 2) + 4 * hi;
        st0[r] = (key      <= qrow) ? st0[r] : -1e30f;
        st1[r] = (key + 32 <= qrow) ? st1[r] : -1e30f;
      }
    }

    // ---- online softmax (per-lane scalars, SC folded into exp) ----
    float tmax = fmaxf(st0[0], st0[1]);
#pragma unroll
    for (int r = 2; r < 16; ++r) tmax = fmaxf(tmax, st0[r]);
#pragma unroll
    for (int r = 0; r < 16; ++r) tmax = fmaxf(tmax, st1[r]);
    tmax = fmaxf(tmax, __shfl_xor(tmax, 32));

    if (!__all(tmax <= m + THRR)) {      // rescale path (rare after tile 0)
      const float mnew  = fmaxf(m, tmax);
      const float al    = __builtin_amdgcn_exp2f((m - mnew) * SC);
#pragma unroll
      for (int r = 0; r < 16; ++r) { o0[r] *= al; o1[r] *= al; }
      l *= al;
      m  = mnew;
      c1 = -m * SC;
    }

    float sum = 0.f;
#pragma unroll
    for (int r = 0; r < 16; ++r) { float pv = __builtin_amdgcn_exp2f(__builtin_fmaf(st0[r], SC, c1)); st0[r] = pv; sum += pv; }
#pragma unroll
    for (int r = 0; r < 16; ++r) { float pv = __builtin_amdgcn_exp2f(__builtin_fmaf(st1[r], SC, c1)); st1[r] = pv; sum += pv; }
    sum += __shfl_xor(sum, 32);
    l += sum;

    // ---- pack P^T into PV B-fragments via v_cvt_pk_bf16_f32 ----
    union U8 { bf16x8 v; unsigned int u[4]; };
    U8 pf[4];
#pragma unroll
    for (int j = 0; j < 4; ++j) {
      pf[0].u[j] = cvtpk(st0[2 * j],     st0[2 * j + 1]);
      pf[1].u[j] = cvtpk(st0[8 + 2 * j], st0[8 + 2 * j + 1]);
      pf[2].u[j] = cvtpk(st1[2 * j],     st1[2 * j + 1]);
      pf[3].u[j] = cvtpk(st1[8 + 2 * j], st1[8 + 2 * j + 1]);
    }

    // ---- PV: O^T[d][q] += V^T[d][k] * P^T[k][q]; slot-ordered V = one b128 ----
    const int ncf = (!last || has1) ? 4 : 2;
    __builtin_amdgcn_s_setprio(1);
#pragma unroll
    for (int dh = 0; dh < 2; ++dh) {
      const unsigned short* Vrow = &Vt[(dh * 32 + qi) * 64];
      f32x16 oc = dh ? o1 : o0;
#pragma unroll
      for (int c = 0; c < 4; ++c) {
        if (c >= ncf) break;
        bf16x8 vf = *(const bf16x8*)&Vrow[(((2 * c + hi) ^ swz) << 3)];
        oc = __builtin_amdgcn_mfma_f32_32x32x16_bf16(vf, pf[c].v, oc, 0, 0, 0);
      }
      if (dh) o1 = oc; else o0 = oc;
    }
    __builtin_amdgcn_s_setprio(0);

    p = (p > 1) ? 0 : p + 1;
  }

  // ---- normalize + store bf16 ----
  const float inv = 1.0f / l;
  unsigned short* orow = ob + (size_t)(b * T_ + qrow) * (H_ * D_) + h * D_;
#pragma unroll
  for (int dh = 0; dh < 2; ++dh) {
    const f32x16 ov = dh ? o1 : o0;
#pragma unroll
    for (int rg = 0; rg < 4; ++rg) {
      const int d0 = 32 * dh + 8 * rg + 4 * hi;
      ushort4 pk;
      pk.x = f2bf(ov[4 * rg + 0] * inv);
      pk.y = f2bf(ov[4 * rg + 1] * inv);
      pk.z = f2bf(ov[4 * rg + 2] * inv);
      pk.w = f2bf(ov[4 * rg + 3] * inv);
      *(ushort4*)(orow + d0) = pk;
    }
  }
#undef STAGE_KV
}

// ---------------------------------------------------------------------------
extern "C" void kernel_launch(void* const* d_in, const int* in_sizes, int n_in,
                              void* d_out, int out_size, void* d_ws, size_t ws_size,
                              hipStream_t stream) {
  const float* x    = (const float*)d_in[0];
  const float* cosT = (const float*)d_in[1];
  const float* sinT = (const float*)d_in[2];
  const float* wq   = (const float*)d_in[3];
  const float* wk   = (const float*)d_in[4];
  const float* wv   = (const float*)d_in[5];
  const float* wo   = (const float*)d_in[6];

  float* y    = (float*)d_out;                                  // B*T*C
  float* kout = (float*)d_out + (size_t)B_ * T_ * C_;           // B*Hk*T*D
  float* vout = kout + (size_t)B_ * HK_ * T_ * D_;

  // Workspace layout (peak 56,623,104 B; reuses are stream-ordered):
  char* ws = (char*)d_ws;
  unsigned short* x_bf   = (unsigned short*)(ws);               // 16,777,216 B
  unsigned short* q_bf   = x_bf;                                // reuse after GEMM1
  unsigned short* wqkv   = (unsigned short*)(ws + 16777216);    // 10,485,760 B
  unsigned short* k_bf   = wqkv;                                //  2,097,152 B (reuse)
  unsigned short* v_t    = (unsigned short*)(ws + 18874368);    //  2,097,152 B (reuse)
  unsigned short* qkv_bf = (unsigned short*)(ws + 27262976);    // 20,971,520 B
  unsigned short* o_bf   = qkv_bf;                              // reuse after rope
  unsigned short* wo_bf  = (unsigned short*)(ws + 48234496);    //  8,388,608 B -> end 56,623,104

  const int M = B_ * T_;  // 4096

  f32_to_bf16<<<8192, 256, 0, stream>>>(x,  x_bf, 2097152);
  f32_to_bf16<<<4096, 256, 0, stream>>>(wq, wqkv,                 1048576);
  f32_to_bf16<<<512,  256, 0, stream>>>(wk, wqkv + 2048 * 2048,   131072);
  f32_to_bf16<<<512,  256, 0, stream>>>(wv, wqkv + 2304 * 2048,   131072);

  gemm_bf16<true><<<dim3(2560 / 128, M / 128), 256, 0, stream>>>(x_bf, wqkv, qkv_bf, M, 2560, C_);

  gqa_rope_q<<<16384, 256, 0, stream>>>(qkv_bf, cosT, sinT, q_bf);
  gqa_rope_k<<<2048,  256, 0, stream>>>(qkv_bf, cosT, sinT, kout, k_bf);
  gqa_v_reorder<<<4096, 256, 0, stream>>>(qkv_bf, vout, v_t);

  f32_to_bf16<<<4096, 256, 0, stream>>>(wo, wo_bf, 1048576);

  gqa_attn4<<<512, 512, 0, stream>>>(q_bf, k_bf, v_t, o_bf);

  gemm_bf16<false><<<dim3(C_ / 128, M / 128), 256, 0, stream>>>(o_bf, wo_bf, y, M, C_, H_ * D_);
}

// Round 6
// 209.173 us; speedup vs baseline: 3.7933x; 1.0843x over previous
//
#include <hip/hip_runtime.h>
#include <hip/hip_bf16.h>

#define B_ 2
#define T_ 2048
#define C_ 2048
#define H_ 32
#define HK_ 4
#define D_ 64

typedef __attribute__((ext_vector_type(4)))  float f32x4;
typedef __attribute__((ext_vector_type(2)))  float f32x2;
typedef __attribute__((ext_vector_type(16))) float f32x16;
typedef __attribute__((ext_vector_type(8)))  short bf16x8;

static __device__ __forceinline__ unsigned short f2bf(float f) {
  union { __hip_bfloat16 h; unsigned short s; } u;
  u.h = __float2bfloat16(f);
  return u.s;
}
static __device__ __forceinline__ float bf2f(unsigned short s) {
  union { unsigned int u; float f; } u; u.u = ((unsigned int)s) << 16; return u.f;
}
// packed f32 pair -> 2 bf16 (RNE) in one instruction
static __device__ __forceinline__ unsigned int cvtpk(float lo, float hi) {
  unsigned int r;
  asm("v_cvt_pk_bf16_f32 %0, %1, %2" : "=v"(r) : "v"(lo), "v"(hi));
  return r;
}

#define GLD16(gp, lp) __builtin_amdgcn_global_load_lds( \
    (const __attribute__((address_space(1))) unsigned int*)(gp), \
    (__attribute__((address_space(3))) unsigned int*)(unsigned int)(uintptr_t)(lp), 16, 0, 0)

// ---------------------------------------------------------------------------
// f32 -> bf16 convert (vectorized)
// ---------------------------------------------------------------------------
__global__ void f32_to_bf16(const float* __restrict__ src, unsigned short* __restrict__ dst, int n4) {
  const int i = blockIdx.x * blockDim.x + threadIdx.x;
  if (i >= n4) return;
  f32x4 v = *(const f32x4*)(src + 4 * (size_t)i);
  ushort4 o;
  o.x = f2bf(v[0]); o.y = f2bf(v[1]); o.z = f2bf(v[2]); o.w = f2bf(v[3]);
  *(ushort4*)(dst + 4 * (size_t)i) = o;
}

// ---------------------------------------------------------------------------
// GEMM v2: C[M,N] = A[M,K]_bf16 * W[N,K]_bf16^T.
// 128x128 tile, BK=32, 4 waves (2x2, 64x64/wave), TRIPLE-buffered LDS with
// counted vmcnt(4) (prefetch 2 tiles ahead stays in flight across the wait),
// ONE raw s_barrier per tile, chunk-XOR swizzle (pre-swizzled global source,
// swizzled LDS frag reads), setprio around the MFMA cluster.
// ---------------------------------------------------------------------------
template<bool BF16OUT>
__global__ __launch_bounds__(256, 3)
void gemm3(const unsigned short* __restrict__ A, const unsigned short* __restrict__ W,
           void* __restrict__ Cout, int M, int N, int K) {
  __shared__ unsigned short As[3][128 * 32];
  __shared__ unsigned short Ws[3][128 * 32];

  const int tid  = threadIdx.x;
  const int lane = tid & 63;
  const int w    = tid >> 6;
  const int wm   = w >> 1, wn = w & 1;
  const int g    = lane >> 4;
  const int lr   = lane & 15;

  const int bm = blockIdx.y * 128;
  const int bn = blockIdx.x * 128;

  // staging map: thread tid covers LDS shorts [tid*8, tid*8+8) of a 4KB pass
  //   row = P*64 + (tid>>2), chunk = tid&3, source chunk pre-XOR'd by row&3
  const int srow = tid >> 2;                  // 0..63
  const int sc   = (tid & 3) ^ (srow & 3);    // pre-swizzled 16B chunk
  const unsigned short* Ag = A + (size_t)(bm + srow) * K + sc * 8;
  const unsigned short* Wg = W + (size_t)(bn + srow) * K + sc * 8;

#define STAGE3(buf, k0) do { \
    GLD16(Ag + (k0),                  &As[buf][       w * 512]); \
    GLD16(Ag + (size_t)64 * K + (k0), &As[buf][2048 + w * 512]); \
    GLD16(Wg + (k0),                  &Ws[buf][       w * 512]); \
    GLD16(Wg + (size_t)64 * K + (k0), &Ws[buf][2048 + w * 512]); \
  } while (0)

  f32x4 acc[4][4] = {};

  const int nt = K >> 5;          // 64 for K=2048
  STAGE3(0, 0);
  STAGE3(1, 32);

  for (int t = 0; t < nt; ++t) {
    if (t + 1 < nt) asm volatile("s_waitcnt vmcnt(4)" ::: "memory");
    else            asm volatile("s_waitcnt vmcnt(0)" ::: "memory");
    asm volatile("s_barrier" ::: "memory");

    if (t + 2 < nt) {
      const int nb = (t + 2) % 3;
      STAGE3(nb, (size_t)(t + 2) * 32);
    }

    const unsigned short* At = &As[t % 3][0];
    const unsigned short* Wt = &Ws[t % 3][0];

    bf16x8 af[4], wf[4];
#pragma unroll
    for (int m = 0; m < 4; m++) {
      const int row = wm * 64 + m * 16 + lr;
      af[m] = *(const bf16x8*)&At[row * 32 + ((g ^ (row & 3)) << 3)];
    }
#pragma unroll
    for (int n = 0; n < 4; n++) {
      const int row = wn * 64 + n * 16 + lr;
      wf[n] = *(const bf16x8*)&Wt[row * 32 + ((g ^ (row & 3)) << 3)];
    }
    __builtin_amdgcn_s_setprio(1);
#pragma unroll
    for (int m = 0; m < 4; m++)
#pragma unroll
      for (int n = 0; n < 4; n++)
        acc[m][n] = __builtin_amdgcn_mfma_f32_16x16x32_bf16(af[m], wf[n], acc[m][n], 0, 0, 0);
    __builtin_amdgcn_s_setprio(0);
  }
#undef STAGE3

  // C/D layout: col = lane&15, row = 4*(lane>>4) + reg
#pragma unroll
  for (int m = 0; m < 4; m++) {
    const int row = bm + wm * 64 + m * 16 + g * 4;
#pragma unroll
    for (int n = 0; n < 4; n++) {
      const int col = bn + wn * 64 + n * 16 + lr;
#pragma unroll
      for (int r = 0; r < 4; r++) {
        if (BF16OUT)
          ((unsigned short*)Cout)[(size_t)(row + r) * N + col] = f2bf(acc[m][n][r]);
        else
          ((float*)Cout)[(size_t)(row + r) * N + col] = acc[m][n][r];
      }
    }
  }
}

// ---------------------------------------------------------------------------
// RoPE q: qkv_bf (B*T, 2560) cols [0,2048) -> q_bf (B,H,T,D) bf16
// ---------------------------------------------------------------------------
__global__ void gqa_rope_q(const unsigned short* __restrict__ qkv,
                           const float* __restrict__ cosT,
                           const float* __restrict__ sinT,
                           unsigned short* __restrict__ qb) {
  const int idx = blockIdx.x * blockDim.x + threadIdx.x; // B*T*H*32
  const int i  = idx & 31;
  const int h  = (idx >> 5) & 31;
  const int bt = idx >> 10;
  const int t  = bt & (T_ - 1);
  const int b  = bt >> 11;

  const unsigned int qv = *(const unsigned int*)(qkv + (size_t)bt * 2560 + h * D_ + 2 * i);
  const float x1 = bf2f((unsigned short)(qv & 0xffff));
  const float x2 = bf2f((unsigned short)(qv >> 16));
  const float c = cosT[t * D_ + 2 * i];
  const float s = sinT[t * D_ + 2 * i];
  const float o0 = x1 * c - x2 * s;
  const float o1 = x2 * c + x1 * s;
  const size_t o = ((size_t)(b * H_ + h) * T_ + t) * D_ + 2 * i;
  *(unsigned int*)(qb + o) = (unsigned int)f2bf(o0) | ((unsigned int)f2bf(o1) << 16);
}

// ---------------------------------------------------------------------------
// RoPE k: qkv_bf cols [2048,2304) -> kout f32 (B,Hk,T,D) + k_bf bf16 same
// ---------------------------------------------------------------------------
__global__ void gqa_rope_k(const unsigned short* __restrict__ qkv,
                           const float* __restrict__ cosT,
                           const float* __restrict__ sinT,
                           float* __restrict__ kout,
                           unsigned short* __restrict__ kb) {
  const int idx = blockIdx.x * blockDim.x + threadIdx.x; // B*T*Hk*32
  const int i  = idx & 31;
  const int hk = (idx >> 5) & 3;
  const int bt = idx >> 7;
  const int t  = bt & (T_ - 1);
  const int b  = bt >> 11;

  const unsigned int kv = *(const unsigned int*)(qkv + (size_t)bt * 2560 + 2048 + hk * D_ + 2 * i);
  const float x1 = bf2f((unsigned short)(kv & 0xffff));
  const float x2 = bf2f((unsigned short)(kv >> 16));
  const float c = cosT[t * D_ + 2 * i];
  const float s = sinT[t * D_ + 2 * i];
  const float o0 = x1 * c - x2 * s;
  const float o1 = x2 * c + x1 * s;
  const size_t o = ((size_t)(b * HK_ + hk) * T_ + t) * D_ + 2 * i;
  f32x2 ov; ov[0] = o0; ov[1] = o1;
  *(f32x2*)(kout + o) = ov;
  *(unsigned int*)(kb + o) = (unsigned int)f2bf(o0) | ((unsigned int)f2bf(o1) << 16);
}

// ---------------------------------------------------------------------------
// v: qkv_bf cols [2304,2560) -> vout f32 (B,Hk,T,D) + vT bf16 (B,Hk,D,T)
// vT key-dim stored in MFMA-slot order per 16-key group.
// ---------------------------------------------------------------------------
__global__ void gqa_v_reorder(const unsigned short* __restrict__ qkv,
                              float* __restrict__ vout,
                              unsigned short* __restrict__ vt) {
  const int idx = blockIdx.x * blockDim.x + threadIdx.x; // B*T*Hk*D = 1048576
  const int d  = idx & 63;
  const int hk = (idx >> 6) & 3;
  const int bt = idx >> 8;
  const int t  = bt & (T_ - 1);
  const int b  = bt >> 11;

  const unsigned short v = qkv[(size_t)bt * 2560 + 2304 + hk * D_ + d];
  vout[((size_t)(b * HK_ + hk) * T_ + t) * D_ + d] = bf2f(v);

  const int tm   = t & 15;
  const int tpos = (t & ~15) | ((tm & 3) + ((tm >> 3) << 2) + ((tm & 4) << 1));
  vt[((size_t)(b * HK_ + hk) * D_ + d) * T_ + tpos] = v;
}

// ---------------------------------------------------------------------------
// Flash attention v4 (unchanged from round 5)
// ---------------------------------------------------------------------------
__global__ __launch_bounds__(512, 4)
void gqa_attn4(const unsigned short* __restrict__ qb,
               const unsigned short* __restrict__ kb,
               const unsigned short* __restrict__ vt,
               unsigned short* __restrict__ ob) {
  __shared__ unsigned short Ks[3][4096];   // [64 keys][64 d], 16B-chunk XOR-swizzled
  __shared__ unsigned short Vs[3][4096];   // [64 d][64 key-slots], same swizzle

  const int tid  = threadIdx.x;
  const int lane = tid & 63;
  const int w    = tid >> 6;      // 0..7
  const int qi   = lane & 31;
  const int hi   = lane >> 5;

  const int qt = 63 - (int)(blockIdx.x >> 3);   // heavy q-tiles first
  const int go = blockIdx.x & 7;                // (b,hk) octet
  const int b  = go >> 2;
  const int hk = go & 3;
  const int h  = hk * 8 + w;
  const int bh = b * H_ + h;

  const int qbase = qt * 32;
  const int qrow  = qbase + qi;

  const unsigned short* qptr = qb + ((size_t)bh * T_ + qrow) * D_ + 8 * hi;
  bf16x8 qf[4];
#pragma unroll
  for (int c = 0; c < 4; c++) qf[c] = *(const bf16x8*)(qptr + 16 * c);

  const int srow   = lane >> 3;
  const int schunk = (lane & 7) ^ srow;
  const int krow   = 8 * w + srow;
  const unsigned short* gK = kb + (size_t)(b * HK_ + hk) * T_ * D_ + (size_t)krow * D_ + schunk * 8;
  const unsigned short* gV = vt + (size_t)(b * HK_ + hk) * D_ * T_ + (size_t)krow * T_ + schunk * 8;
  unsigned short* ldsK = &Ks[0][w * 512];
  unsigned short* ldsV = &Vs[0][w * 512];

#define STAGE_KV(pp, kk0) do { \
    GLD16(gK + (size_t)(kk0) * D_, ldsK + (pp) * 4096); \
    GLD16(gV + (kk0),              ldsV + (pp) * 4096); \
  } while (0)

  f32x16 o0 = {}, o1 = {};           // O^T: col q = lane&31; rows d
  float m = -1e30f, l = 0.f;
  float c1 = 0.f;
  const float SC   = 0.125f * 1.44269504089f;
  const float THRR = 44.3614195f;              // 8 / SC
  const int   swz  = qi & 7;

  const int nt = ((qbase + 31) >> 6) + 1;
  STAGE_KV(0, 0);
  if (nt > 1) STAGE_KV(1, 64);

  int p = 0;
  for (int it = 0; it < nt; ++it) {
    const int kb0 = it * 64;
    const bool last = (it == nt - 1);
    const bool has1 = (kb0 + 32 <= qbase + 31);

    asm volatile("s_waitcnt lgkmcnt(0)" ::: "memory");
    if (it + 1 < nt) asm volatile("s_waitcnt vmcnt(2)" ::: "memory");
    else             asm volatile("s_waitcnt vmcnt(0)" ::: "memory");
    asm volatile("s_barrier" ::: "memory");
    if (it + 2 < nt) STAGE_KV((p + 2 > 2) ? p - 1 : p + 2, kb0 + 128);

    const unsigned short* Kt = &Ks[0][0] + p * 4096;
    const unsigned short* Vt = &Vs[0][0] + p * 4096;

    f32x16 st0 = {}, st1 = {};
    __builtin_amdgcn_s_setprio(1);
#pragma unroll
    for (int c = 0; c < 4; c++) {
      bf16x8 kf = *(const bf16x8*)&Kt[qi * 64 + (((hi + 2 * c) ^ swz) << 3)];
      st0 = __builtin_amdgcn_mfma_f32_32x32x16_bf16(kf, qf[c], st0, 0, 0, 0);
    }
    if (!last || has1) {
#pragma unroll
      for (int c = 0; c < 4; c++) {
        bf16x8 kf = *(const bf16x8*)&Kt[(32 + qi) * 64 + (((hi + 2 * c) ^ swz) << 3)];
        st1 = __builtin_amdgcn_mfma_f32_32x32x16_bf16(kf, qf[c], st1, 0, 0, 0);
      }
    }
    __builtin_amdgcn_s_setprio(0);

    if (last) {
#pragma unroll
      for (int r = 0; r < 16; ++r) {
        const int key = kb0 + (r & 3) + 8 * (r >> 2) + 4 * hi;
        st0[r] = (key      <= qrow) ? st0[r] : -1e30f;
        st1[r] = (key + 32 <= qrow) ? st1[r] : -1e30f;
      }
    }

    float tmax = fmaxf(st0[0], st0[1]);
#pragma unroll
    for (int r = 2; r < 16; ++r) tmax = fmaxf(tmax, st0[r]);
#pragma unroll
    for (int r = 0; r < 16; ++r) tmax = fmaxf(tmax, st1[r]);
    tmax = fmaxf(tmax, __shfl_xor(tmax, 32));

    if (!__all(tmax <= m + THRR)) {
      const float mnew  = fmaxf(m, tmax);
      const float al    = __builtin_amdgcn_exp2f((m - mnew) * SC);
#pragma unroll
      for (int r = 0; r < 16; ++r) { o0[r] *= al; o1[r] *= al; }
      l *= al;
      m  = mnew;
      c1 = -m * SC;
    }

    float sum = 0.f;
#pragma unroll
    for (int r = 0; r < 16; ++r) { float pv = __builtin_amdgcn_exp2f(__builtin_fmaf(st0[r], SC, c1)); st0[r] = pv; sum += pv; }
#pragma unroll
    for (int r = 0; r < 16; ++r) { float pv = __builtin_amdgcn_exp2f(__builtin_fmaf(st1[r], SC, c1)); st1[r] = pv; sum += pv; }
    sum += __shfl_xor(sum, 32);
    l += sum;

    union U8 { bf16x8 v; unsigned int u[4]; };
    U8 pf[4];
#pragma unroll
    for (int j = 0; j < 4; ++j) {
      pf[0].u[j] = cvtpk(st0[2 * j],     st0[2 * j + 1]);
      pf[1].u[j] = cvtpk(st0[8 + 2 * j], st0[8 + 2 * j + 1]);
      pf[2].u[j] = cvtpk(st1[2 * j],     st1[2 * j + 1]);
      pf[3].u[j] = cvtpk(st1[8 + 2 * j], st1[8 + 2 * j + 1]);
    }

    const int ncf = (!last || has1) ? 4 : 2;
    __builtin_amdgcn_s_setprio(1);
#pragma unroll
    for (int dh = 0; dh < 2; ++dh) {
      const unsigned short* Vrow = &Vt[(dh * 32 + qi) * 64];
      f32x16 oc = dh ? o1 : o0;
#pragma unroll
      for (int c = 0; c < 4; ++c) {
        if (c >= ncf) break;
        bf16x8 vf = *(const bf16x8*)&Vrow[(((2 * c + hi) ^ swz) << 3)];
        oc = __builtin_amdgcn_mfma_f32_32x32x16_bf16(vf, pf[c].v, oc, 0, 0, 0);
      }
      if (dh) o1 = oc; else o0 = oc;
    }
    __builtin_amdgcn_s_setprio(0);

    p = (p > 1) ? 0 : p + 1;
  }

  const float inv = 1.0f / l;
  unsigned short* orow = ob + (size_t)(b * T_ + qrow) * (H_ * D_) + h * D_;
#pragma unroll
  for (int dh = 0; dh < 2; ++dh) {
    const f32x16 ov = dh ? o1 : o0;
#pragma unroll
    for (int rg = 0; rg < 4; ++rg) {
      const int d0 = 32 * dh + 8 * rg + 4 * hi;
      ushort4 pk;
      pk.x = f2bf(ov[4 * rg + 0] * inv);
      pk.y = f2bf(ov[4 * rg + 1] * inv);
      pk.z = f2bf(ov[4 * rg + 2] * inv);
      pk.w = f2bf(ov[4 * rg + 3] * inv);
      *(ushort4*)(orow + d0) = pk;
    }
  }
#undef STAGE_KV
}

// ---------------------------------------------------------------------------
extern "C" void kernel_launch(void* const* d_in, const int* in_sizes, int n_in,
                              void* d_out, int out_size, void* d_ws, size_t ws_size,
                              hipStream_t stream) {
  const float* x    = (const float*)d_in[0];
  const float* cosT = (const float*)d_in[1];
  const float* sinT = (const float*)d_in[2];
  const float* wq   = (const float*)d_in[3];
  const float* wk   = (const float*)d_in[4];
  const float* wv   = (const float*)d_in[5];
  const float* wo   = (const float*)d_in[6];

  float* y    = (float*)d_out;                                  // B*T*C
  float* kout = (float*)d_out + (size_t)B_ * T_ * C_;           // B*Hk*T*D
  float* vout = kout + (size_t)B_ * HK_ * T_ * D_;

  // Workspace layout (peak 56,623,104 B; reuses are stream-ordered):
  char* ws = (char*)d_ws;
  unsigned short* x_bf   = (unsigned short*)(ws);               // 16,777,216 B
  unsigned short* q_bf   = x_bf;                                // reuse after GEMM1
  unsigned short* wqkv   = (unsigned short*)(ws + 16777216);    // 10,485,760 B
  unsigned short* k_bf   = wqkv;                                //  2,097,152 B (reuse)
  unsigned short* v_t    = (unsigned short*)(ws + 18874368);    //  2,097,152 B (reuse)
  unsigned short* qkv_bf = (unsigned short*)(ws + 27262976);    // 20,971,520 B
  unsigned short* o_bf   = qkv_bf;                              // reuse after rope
  unsigned short* wo_bf  = (unsigned short*)(ws + 48234496);    //  8,388,608 B -> end 56,623,104

  const int M = B_ * T_;  // 4096

  f32_to_bf16<<<8192, 256, 0, stream>>>(x,  x_bf, 2097152);
  f32_to_bf16<<<4096, 256, 0, stream>>>(wq, wqkv,                 1048576);
  f32_to_bf16<<<512,  256, 0, stream>>>(wk, wqkv + 2048 * 2048,   131072);
  f32_to_bf16<<<512,  256, 0, stream>>>(wv, wqkv + 2304 * 2048,   131072);

  gemm3<true><<<dim3(2560 / 128, M / 128), 256, 0, stream>>>(x_bf, wqkv, qkv_bf, M, 2560, C_);

  gqa_rope_q<<<16384, 256, 0, stream>>>(qkv_bf, cosT, sinT, q_bf);
  gqa_rope_k<<<2048,  256, 0, stream>>>(qkv_bf, cosT, sinT, kout, k_bf);
  gqa_v_reorder<<<4096, 256, 0, stream>>>(qkv_bf, vout, v_t);

  f32_to_bf16<<<4096, 256, 0, stream>>>(wo, wo_bf, 1048576);

  gqa_attn4<<<512, 512, 0, stream>>>(q_bf, k_bf, v_t, o_bf);

  gemm3<false><<<dim3(C_ / 128, M / 128), 256, 0, stream>>>(o_bf, wo_bf, y, M, C_, H_ * D_);
}

// Round 7
// 206.799 us; speedup vs baseline: 3.8368x; 1.0115x over previous
//
#include <hip/hip_runtime.h>
#include <hip/hip_bf16.h>

#define B_ 2
#define T_ 2048
#define C_ 2048
#define H_ 32
#define HK_ 4
#define D_ 64

typedef __attribute__((ext_vector_type(4)))  float f32x4;
typedef __attribute__((ext_vector_type(2)))  float f32x2;
typedef __attribute__((ext_vector_type(16))) float f32x16;
typedef __attribute__((ext_vector_type(8)))  short bf16x8;

static __device__ __forceinline__ unsigned short f2bf(float f) {
  union { __hip_bfloat16 h; unsigned short s; } u;
  u.h = __float2bfloat16(f);
  return u.s;
}
static __device__ __forceinline__ float bf2f(unsigned short s) {
  union { unsigned int u; float f; } u; u.u = ((unsigned int)s) << 16; return u.f;
}
// packed f32 pair -> 2 bf16 (RNE) in one instruction
static __device__ __forceinline__ unsigned int cvtpk(float lo, float hi) {
  unsigned int r;
  asm("v_cvt_pk_bf16_f32 %0, %1, %2" : "=v"(r) : "v"(lo), "v"(hi));
  return r;
}

#define GLD16(gp, lp) __builtin_amdgcn_global_load_lds( \
    (const __attribute__((address_space(1))) unsigned int*)(gp), \
    (__attribute__((address_space(3))) unsigned int*)(unsigned int)(uintptr_t)(lp), 16, 0, 0)

// ---------------------------------------------------------------------------
// f32 -> bf16 convert (vectorized)
// ---------------------------------------------------------------------------
__global__ void f32_to_bf16(const float* __restrict__ src, unsigned short* __restrict__ dst, int n4) {
  const int i = blockIdx.x * blockDim.x + threadIdx.x;
  if (i >= n4) return;
  f32x4 v = *(const f32x4*)(src + 4 * (size_t)i);
  ushort4 o;
  o.x = f2bf(v[0]); o.y = f2bf(v[1]); o.z = f2bf(v[2]); o.w = f2bf(v[3]);
  *(ushort4*)(dst + 4 * (size_t)i) = o;
}

// ---------------------------------------------------------------------------
// GEMM v3: C[M,N] = A[M,K]_bf16 * W[N,K]_bf16^T.
// BM=128, BN=256, BK=64; 8 waves (2 wave-rows x 4 wave-cols), wave tile 64x64.
// Double-buffered LDS (96 KB, 1 block/CU). One barrier per K-tile; the 6
// staging loads for tile t+1 are issued right after the barrier of tile t and
// waited one full iteration later (vmcnt(0) with ~full-tile slack >= HBM
// latency). 8-chunk/row XOR swizzle: pre-swizzled global source, swizzled
// LDS frag reads (2-way residual = free). lgkm waits are compiler-managed
// (frag reads are normal loads). setprio around the MFMA cluster.
// ---------------------------------------------------------------------------
template<bool BF16OUT>
__global__ __launch_bounds__(512, 2)
void gemm256(const unsigned short* __restrict__ A, const unsigned short* __restrict__ W,
             void* __restrict__ Cout, int M, int N, int K) {
  __shared__ unsigned short As[2][128 * 64];   // 32 KB
  __shared__ unsigned short Bs[2][256 * 64];   // 64 KB

  const int tid  = threadIdx.x;
  const int lane = tid & 63;
  const int w    = tid >> 6;       // 0..7
  const int wm   = w >> 2;         // 0..1  (64-row slice of the 128)
  const int wn   = w & 3;          // 0..3  (64-col slice of the 256)
  const int g    = lane >> 4;      // k-group 0..3
  const int lr   = lane & 15;

  const int bm = blockIdx.y * 128;
  const int bn = blockIdx.x * 256;

  // Staging map: per GLD16, lane l writes LDS bytes [base + 16l, +16) =
  // chunk (l&7) of row base_row + (l>>3). For the swizzled image
  // (chunk' = chunk ^ (row&7)), lane fetches global chunk (l&7)^(l>>3).
  const int sr8 = lane >> 3;              // row-in-group = row&7
  const int sch = (lane & 7) ^ sr8;       // pre-swizzled 16B chunk
  const unsigned short* Ag = A + (size_t)(bm + w * 8 + sr8) * K + sch * 8;
  const unsigned short* Wg = W + (size_t)(bn + w * 8 + sr8) * K + sch * 8;

#define STG(buf, k0) do { \
    GLD16(Ag + (k0),                   &As[buf][(      w * 8) * 64]); \
    GLD16(Ag + (size_t)64  * K + (k0), &As[buf][(64  + w * 8) * 64]); \
    GLD16(Wg + (k0),                   &Bs[buf][(      w * 8) * 64]); \
    GLD16(Wg + (size_t)64  * K + (k0), &Bs[buf][(64  + w * 8) * 64]); \
    GLD16(Wg + (size_t)128 * K + (k0), &Bs[buf][(128 + w * 8) * 64]); \
    GLD16(Wg + (size_t)192 * K + (k0), &Bs[buf][(192 + w * 8) * 64]); \
  } while (0)

  f32x4 acc[4][4] = {};
  const int nt = K >> 6;   // 32 for K=2048
  STG(0, 0);

  for (int t = 0; t < nt; ++t) {
    const int p = t & 1;
    // buf p's 6 loads were issued one full iteration ago -> near-free drain
    asm volatile("s_waitcnt vmcnt(0)" ::: "memory");
    __builtin_amdgcn_s_barrier();
    if (t + 1 < nt) STG(p ^ 1, (t + 1) << 6);

    const unsigned short* At = &As[p][0];
    const unsigned short* Bt = &Bs[p][0];
#pragma unroll
    for (int kh = 0; kh < 2; ++kh) {
      bf16x8 af[4], wf[4];
#pragma unroll
      for (int m = 0; m < 4; m++) {
        const int row = wm * 64 + m * 16 + lr;
        af[m] = *(const bf16x8*)&At[row * 64 + (((g + 4 * kh) ^ (row & 7)) << 3)];
      }
#pragma unroll
      for (int n = 0; n < 4; n++) {
        const int row = wn * 64 + n * 16 + lr;
        wf[n] = *(const bf16x8*)&Bt[row * 64 + (((g + 4 * kh) ^ (row & 7)) << 3)];
      }
      __builtin_amdgcn_s_setprio(1);
#pragma unroll
      for (int m = 0; m < 4; m++)
#pragma unroll
        for (int n = 0; n < 4; n++)
          acc[m][n] = __builtin_amdgcn_mfma_f32_16x16x32_bf16(af[m], wf[n], acc[m][n], 0, 0, 0);
      __builtin_amdgcn_s_setprio(0);
    }
  }
#undef STG

  // C/D layout: col = lane&15, row = 4*(lane>>4) + reg
#pragma unroll
  for (int m = 0; m < 4; m++) {
    const int row = bm + wm * 64 + m * 16 + g * 4;
#pragma unroll
    for (int n = 0; n < 4; n++) {
      const int col = bn + wn * 64 + n * 16 + lr;
#pragma unroll
      for (int r = 0; r < 4; r++) {
        if (BF16OUT)
          ((unsigned short*)Cout)[(size_t)(row + r) * N + col] = f2bf(acc[m][n][r]);
        else
          ((float*)Cout)[(size_t)(row + r) * N + col] = acc[m][n][r];
      }
    }
  }
}

// ---------------------------------------------------------------------------
// RoPE q: qkv_bf (B*T, 2560) cols [0,2048) -> q_bf (B,H,T,D) bf16
// ---------------------------------------------------------------------------
__global__ void gqa_rope_q(const unsigned short* __restrict__ qkv,
                           const float* __restrict__ cosT,
                           const float* __restrict__ sinT,
                           unsigned short* __restrict__ qb) {
  const int idx = blockIdx.x * blockDim.x + threadIdx.x; // B*T*H*32
  const int i  = idx & 31;
  const int h  = (idx >> 5) & 31;
  const int bt = idx >> 10;
  const int t  = bt & (T_ - 1);
  const int b  = bt >> 11;

  const unsigned int qv = *(const unsigned int*)(qkv + (size_t)bt * 2560 + h * D_ + 2 * i);
  const float x1 = bf2f((unsigned short)(qv & 0xffff));
  const float x2 = bf2f((unsigned short)(qv >> 16));
  const float c = cosT[t * D_ + 2 * i];
  const float s = sinT[t * D_ + 2 * i];
  const float o0 = x1 * c - x2 * s;
  const float o1 = x2 * c + x1 * s;
  const size_t o = ((size_t)(b * H_ + h) * T_ + t) * D_ + 2 * i;
  *(unsigned int*)(qb + o) = (unsigned int)f2bf(o0) | ((unsigned int)f2bf(o1) << 16);
}

// ---------------------------------------------------------------------------
// RoPE k: qkv_bf cols [2048,2304) -> kout f32 (B,Hk,T,D) + k_bf bf16 same
// ---------------------------------------------------------------------------
__global__ void gqa_rope_k(const unsigned short* __restrict__ qkv,
                           const float* __restrict__ cosT,
                           const float* __restrict__ sinT,
                           float* __restrict__ kout,
                           unsigned short* __restrict__ kb) {
  const int idx = blockIdx.x * blockDim.x + threadIdx.x; // B*T*Hk*32
  const int i  = idx & 31;
  const int hk = (idx >> 5) & 3;
  const int bt = idx >> 7;
  const int t  = bt & (T_ - 1);
  const int b  = bt >> 11;

  const unsigned int kv = *(const unsigned int*)(qkv + (size_t)bt * 2560 + 2048 + hk * D_ + 2 * i);
  const float x1 = bf2f((unsigned short)(kv & 0xffff));
  const float x2 = bf2f((unsigned short)(kv >> 16));
  const float c = cosT[t * D_ + 2 * i];
  const float s = sinT[t * D_ + 2 * i];
  const float o0 = x1 * c - x2 * s;
  const float o1 = x2 * c + x1 * s;
  const size_t o = ((size_t)(b * HK_ + hk) * T_ + t) * D_ + 2 * i;
  f32x2 ov; ov[0] = o0; ov[1] = o1;
  *(f32x2*)(kout + o) = ov;
  *(unsigned int*)(kb + o) = (unsigned int)f2bf(o0) | ((unsigned int)f2bf(o1) << 16);
}

// ---------------------------------------------------------------------------
// v: qkv_bf cols [2304,2560) -> vout f32 (B,Hk,T,D) + vT bf16 (B,Hk,D,T)
// vT key-dim stored in MFMA-slot order per 16-key group.
// ---------------------------------------------------------------------------
__global__ void gqa_v_reorder(const unsigned short* __restrict__ qkv,
                              float* __restrict__ vout,
                              unsigned short* __restrict__ vt) {
  const int idx = blockIdx.x * blockDim.x + threadIdx.x; // B*T*Hk*D = 1048576
  const int d  = idx & 63;
  const int hk = (idx >> 6) & 3;
  const int bt = idx >> 8;
  const int t  = bt & (T_ - 1);
  const int b  = bt >> 11;

  const unsigned short v = qkv[(size_t)bt * 2560 + 2304 + hk * D_ + d];
  vout[((size_t)(b * HK_ + hk) * T_ + t) * D_ + d] = bf2f(v);

  const int tm   = t & 15;
  const int tpos = (t & ~15) | ((tm & 3) + ((tm >> 3) << 2) + ((tm & 4) << 1));
  vt[((size_t)(b * HK_ + hk) * D_ + d) * T_ + tpos] = v;
}

// ---------------------------------------------------------------------------
// Flash attention v4 (unchanged)
// ---------------------------------------------------------------------------
__global__ __launch_bounds__(512, 4)
void gqa_attn4(const unsigned short* __restrict__ qb,
               const unsigned short* __restrict__ kb,
               const unsigned short* __restrict__ vt,
               unsigned short* __restrict__ ob) {
  __shared__ unsigned short Ks[3][4096];
  __shared__ unsigned short Vs[3][4096];

  const int tid  = threadIdx.x;
  const int lane = tid & 63;
  const int w    = tid >> 6;
  const int qi   = lane & 31;
  const int hi   = lane >> 5;

  const int qt = 63 - (int)(blockIdx.x >> 3);
  const int go = blockIdx.x & 7;
  const int b  = go >> 2;
  const int hk = go & 3;
  const int h  = hk * 8 + w;
  const int bh = b * H_ + h;

  const int qbase = qt * 32;
  const int qrow  = qbase + qi;

  const unsigned short* qptr = qb + ((size_t)bh * T_ + qrow) * D_ + 8 * hi;
  bf16x8 qf[4];
#pragma unroll
  for (int c = 0; c < 4; c++) qf[c] = *(const bf16x8*)(qptr + 16 * c);

  const int srow   = lane >> 3;
  const int schunk = (lane & 7) ^ srow;
  const int krow   = 8 * w + srow;
  const unsigned short* gK = kb + (size_t)(b * HK_ + hk) * T_ * D_ + (size_t)krow * D_ + schunk * 8;
  const unsigned short* gV = vt + (size_t)(b * HK_ + hk) * D_ * T_ + (size_t)krow * T_ + schunk * 8;
  unsigned short* ldsK = &Ks[0][w * 512];
  unsigned short* ldsV = &Vs[0][w * 512];

#define STAGE_KV(pp, kk0) do { \
    GLD16(gK + (size_t)(kk0) * D_, ldsK + (pp) * 4096); \
    GLD16(gV + (kk0),              ldsV + (pp) * 4096); \
  } while (0)

  f32x16 o0 = {}, o1 = {};
  float m = -1e30f, l = 0.f;
  float c1 = 0.f;
  const float SC   = 0.125f * 1.44269504089f;
  const float THRR = 44.3614195f;
  const int   swz  = qi & 7;

  const int nt = ((qbase + 31) >> 6) + 1;
  STAGE_KV(0, 0);
  if (nt > 1) STAGE_KV(1, 64);

  int p = 0;
  for (int it = 0; it < nt; ++it) {
    const int kb0 = it * 64;
    const bool last = (it == nt - 1);
    const bool has1 = (kb0 + 32 <= qbase + 31);

    asm volatile("s_waitcnt lgkmcnt(0)" ::: "memory");
    if (it + 1 < nt) asm volatile("s_waitcnt vmcnt(2)" ::: "memory");
    else             asm volatile("s_waitcnt vmcnt(0)" ::: "memory");
    asm volatile("s_barrier" ::: "memory");
    if (it + 2 < nt) STAGE_KV((p + 2 > 2) ? p - 1 : p + 2, kb0 + 128);

    const unsigned short* Kt = &Ks[0][0] + p * 4096;
    const unsigned short* Vt = &Vs[0][0] + p * 4096;

    f32x16 st0 = {}, st1 = {};
    __builtin_amdgcn_s_setprio(1);
#pragma unroll
    for (int c = 0; c < 4; c++) {
      bf16x8 kf = *(const bf16x8*)&Kt[qi * 64 + (((hi + 2 * c) ^ swz) << 3)];
      st0 = __builtin_amdgcn_mfma_f32_32x32x16_bf16(kf, qf[c], st0, 0, 0, 0);
    }
    if (!last || has1) {
#pragma unroll
      for (int c = 0; c < 4; c++) {
        bf16x8 kf = *(const bf16x8*)&Kt[(32 + qi) * 64 + (((hi + 2 * c) ^ swz) << 3)];
        st1 = __builtin_amdgcn_mfma_f32_32x32x16_bf16(kf, qf[c], st1, 0, 0, 0);
      }
    }
    __builtin_amdgcn_s_setprio(0);

    if (last) {
#pragma unroll
      for (int r = 0; r < 16; ++r) {
        const int key = kb0 + (r & 3) + 8 * (r >> 2) + 4 * hi;
        st0[r] = (key      <= qrow) ? st0[r] : -1e30f;
        st1[r] = (key + 32 <= qrow) ? st1[r] : -1e30f;
      }
    }

    float tmax = fmaxf(st0[0], st0[1]);
#pragma unroll
    for (int r = 2; r < 16; ++r) tmax = fmaxf(tmax, st0[r]);
#pragma unroll
    for (int r = 0; r < 16; ++r) tmax = fmaxf(tmax, st1[r]);
    tmax = fmaxf(tmax, __shfl_xor(tmax, 32));

    if (!__all(tmax <= m + THRR)) {
      const float mnew  = fmaxf(m, tmax);
      const float al    = __builtin_amdgcn_exp2f((m - mnew) * SC);
#pragma unroll
      for (int r = 0; r < 16; ++r) { o0[r] *= al; o1[r] *= al; }
      l *= al;
      m  = mnew;
      c1 = -m * SC;
    }

    float sum = 0.f;
#pragma unroll
    for (int r = 0; r < 16; ++r) { float pv = __builtin_amdgcn_exp2f(__builtin_fmaf(st0[r], SC, c1)); st0[r] = pv; sum += pv; }
#pragma unroll
    for (int r = 0; r < 16; ++r) { float pv = __builtin_amdgcn_exp2f(__builtin_fmaf(st1[r], SC, c1)); st1[r] = pv; sum += pv; }
    sum += __shfl_xor(sum, 32);
    l += sum;

    union U8 { bf16x8 v; unsigned int u[4]; };
    U8 pf[4];
#pragma unroll
    for (int j = 0; j < 4; ++j) {
      pf[0].u[j] = cvtpk(st0[2 * j],     st0[2 * j + 1]);
      pf[1].u[j] = cvtpk(st0[8 + 2 * j], st0[8 + 2 * j + 1]);
      pf[2].u[j] = cvtpk(st1[2 * j],     st1[2 * j + 1]);
      pf[3].u[j] = cvtpk(st1[8 + 2 * j], st1[8 + 2 * j + 1]);
    }

    const int ncf = (!last || has1) ? 4 : 2;
    __builtin_amdgcn_s_setprio(1);
#pragma unroll
    for (int dh = 0; dh < 2; ++dh) {
      const unsigned short* Vrow = &Vt[(dh * 32 + qi) * 64];
      f32x16 oc = dh ? o1 : o0;
#pragma unroll
      for (int c = 0; c < 4; ++c) {
        if (c >= ncf) break;
        bf16x8 vf = *(const bf16x8*)&Vrow[(((2 * c + hi) ^ swz) << 3)];
        oc = __builtin_amdgcn_mfma_f32_32x32x16_bf16(vf, pf[c].v, oc, 0, 0, 0);
      }
      if (dh) o1 = oc; else o0 = oc;
    }
    __builtin_amdgcn_s_setprio(0);

    p = (p > 1) ? 0 : p + 1;
  }

  const float inv = 1.0f / l;
  unsigned short* orow = ob + (size_t)(b * T_ + qrow) * (H_ * D_) + h * D_;
#pragma unroll
  for (int dh = 0; dh < 2; ++dh) {
    const f32x16 ov = dh ? o1 : o0;
#pragma unroll
    for (int rg = 0; rg < 4; ++rg) {
      const int d0 = 32 * dh + 8 * rg + 4 * hi;
      ushort4 pk;
      pk.x = f2bf(ov[4 * rg + 0] * inv);
      pk.y = f2bf(ov[4 * rg + 1] * inv);
      pk.z = f2bf(ov[4 * rg + 2] * inv);
      pk.w = f2bf(ov[4 * rg + 3] * inv);
      *(ushort4*)(orow + d0) = pk;
    }
  }
#undef STAGE_KV
}

// ---------------------------------------------------------------------------
extern "C" void kernel_launch(void* const* d_in, const int* in_sizes, int n_in,
                              void* d_out, int out_size, void* d_ws, size_t ws_size,
                              hipStream_t stream) {
  const float* x    = (const float*)d_in[0];
  const float* cosT = (const float*)d_in[1];
  const float* sinT = (const float*)d_in[2];
  const float* wq   = (const float*)d_in[3];
  const float* wk   = (const float*)d_in[4];
  const float* wv   = (const float*)d_in[5];
  const float* wo   = (const float*)d_in[6];

  float* y    = (float*)d_out;                                  // B*T*C
  float* kout = (float*)d_out + (size_t)B_ * T_ * C_;           // B*Hk*T*D
  float* vout = kout + (size_t)B_ * HK_ * T_ * D_;

  // Workspace layout (peak 56,623,104 B; reuses are stream-ordered):
  char* ws = (char*)d_ws;
  unsigned short* x_bf   = (unsigned short*)(ws);               // 16,777,216 B
  unsigned short* q_bf   = x_bf;                                // reuse after GEMM1
  unsigned short* wqkv   = (unsigned short*)(ws + 16777216);    // 10,485,760 B
  unsigned short* k_bf   = wqkv;                                //  2,097,152 B (reuse)
  unsigned short* v_t    = (unsigned short*)(ws + 18874368);    //  2,097,152 B (reuse)
  unsigned short* qkv_bf = (unsigned short*)(ws + 27262976);    // 20,971,520 B
  unsigned short* o_bf   = qkv_bf;                              // reuse after rope
  unsigned short* wo_bf  = (unsigned short*)(ws + 48234496);    //  8,388,608 B -> end 56,623,104

  const int M = B_ * T_;  // 4096

  f32_to_bf16<<<8192, 256, 0, stream>>>(x,  x_bf, 2097152);
  f32_to_bf16<<<4096, 256, 0, stream>>>(wq, wqkv,                 1048576);
  f32_to_bf16<<<512,  256, 0, stream>>>(wk, wqkv + 2048 * 2048,   131072);
  f32_to_bf16<<<512,  256, 0, stream>>>(wv, wqkv + 2304 * 2048,   131072);

  gemm256<true><<<dim3(2560 / 256, M / 128), 512, 0, stream>>>(x_bf, wqkv, qkv_bf, M, 2560, C_);

  gqa_rope_q<<<16384, 256, 0, stream>>>(qkv_bf, cosT, sinT, q_bf);
  gqa_rope_k<<<2048,  256, 0, stream>>>(qkv_bf, cosT, sinT, kout, k_bf);
  gqa_v_reorder<<<4096, 256, 0, stream>>>(qkv_bf, vout, v_t);

  f32_to_bf16<<<4096, 256, 0, stream>>>(wo, wo_bf, 1048576);

  gqa_attn4<<<512, 512, 0, stream>>>(q_bf, k_bf, v_t, o_bf);

  gemm256<false><<<dim3(C_ / 256, M / 128), 512, 0, stream>>>(o_bf, wo_bf, y, M, C_, H_ * D_);
}

// Round 8
// 198.698 us; speedup vs baseline: 3.9933x; 1.0408x over previous
//
#include <hip/hip_runtime.h>
#include <hip/hip_bf16.h>

#define B_ 2
#define T_ 2048
#define C_ 2048
#define H_ 32
#define HK_ 4
#define D_ 64

typedef __attribute__((ext_vector_type(4)))  float f32x4;
typedef __attribute__((ext_vector_type(2)))  float f32x2;
typedef __attribute__((ext_vector_type(16))) float f32x16;
typedef __attribute__((ext_vector_type(8)))  short bf16x8;

static __device__ __forceinline__ unsigned short f2bf(float f) {
  union { __hip_bfloat16 h; unsigned short s; } u;
  u.h = __float2bfloat16(f);
  return u.s;
}
static __device__ __forceinline__ float bf2f(unsigned short s) {
  union { unsigned int u; float f; } u; u.u = ((unsigned int)s) << 16; return u.f;
}
static __device__ __forceinline__ unsigned int cvtpk(float lo, float hi) {
  unsigned int r;
  asm("v_cvt_pk_bf16_f32 %0, %1, %2" : "=v"(r) : "v"(lo), "v"(hi));
  return r;
}

#define GLD16(gp, lp) __builtin_amdgcn_global_load_lds( \
    (const __attribute__((address_space(1))) unsigned int*)(gp), \
    (__attribute__((address_space(3))) unsigned int*)(unsigned int)(uintptr_t)(lp), 16, 0, 0)

// ---------------------------------------------------------------------------
// f32 -> bf16 convert (vectorized)
// ---------------------------------------------------------------------------
__global__ void f32_to_bf16(const float* __restrict__ src, unsigned short* __restrict__ dst, int n4) {
  const int i = blockIdx.x * blockDim.x + threadIdx.x;
  if (i >= n4) return;
  f32x4 v = *(const f32x4*)(src + 4 * (size_t)i);
  ushort4 o;
  o.x = f2bf(v[0]); o.y = f2bf(v[1]); o.z = f2bf(v[2]); o.w = f2bf(v[3]);
  *(ushort4*)(dst + 4 * (size_t)i) = o;
}

// ---------------------------------------------------------------------------
// GEMM v4: 128x128 tile, BK=64, 256 threads (4 waves 2x2, 64x64/wave).
// Double-buffered 64KB LDS -> 2 blocks/CU co-resident (the block in its
// vmcnt-drain is hidden by the sibling block's compute). One barrier/tile.
// Chunk-XOR swizzle (pre-swizzled global source). setprio on MFMA cluster.
// EPI=0: plain f32 C.  EPI=1: fused QKV epilogue (RoPE q/k, v slot-reorder).
// ---------------------------------------------------------------------------
template<int EPI>
__global__ __launch_bounds__(256, 2)
void gemm128(const unsigned short* __restrict__ A, const unsigned short* __restrict__ W,
             int M, int N, int K,
             float* __restrict__ Cf,                       // EPI=0
             const float* __restrict__ cosT, const float* __restrict__ sinT,  // EPI=1
             unsigned short* __restrict__ qb, unsigned short* __restrict__ kbf,
             unsigned short* __restrict__ vtb, float* __restrict__ koutf,
             float* __restrict__ voutf) {
  __shared__ unsigned short As[2][128 * 64];   // 16 KB x2
  __shared__ unsigned short Bs[2][128 * 64];   // 16 KB x2

  const int tid  = threadIdx.x;
  const int lane = tid & 63;
  const int w    = tid >> 6;       // 0..3
  const int wm   = w >> 1, wn = w & 1;
  const int g    = lane >> 4;
  const int lr   = lane & 15;

  const int bm = blockIdx.y * 128;
  const int bn = blockIdx.x * 128;

  // staging: pass j covers rows j*32 + w*8 + (lane>>3); chunk (lane&7)^(row&7)
  const int sr8 = lane >> 3;
  const int sch = (lane & 7) ^ sr8;
  const unsigned short* Ag = A + (size_t)(bm + w * 8 + sr8) * K + sch * 8;
  const unsigned short* Wg = W + (size_t)(bn + w * 8 + sr8) * K + sch * 8;

#define STG(buf, k0) do { \
    GLD16(Ag + (k0),                   &As[buf][(     w * 8) * 64]); \
    GLD16(Ag + (size_t)32  * K + (k0), &As[buf][(32 + w * 8) * 64]); \
    GLD16(Ag + (size_t)64  * K + (k0), &As[buf][(64 + w * 8) * 64]); \
    GLD16(Ag + (size_t)96  * K + (k0), &As[buf][(96 + w * 8) * 64]); \
    GLD16(Wg + (k0),                   &Bs[buf][(     w * 8) * 64]); \
    GLD16(Wg + (size_t)32  * K + (k0), &Bs[buf][(32 + w * 8) * 64]); \
    GLD16(Wg + (size_t)64  * K + (k0), &Bs[buf][(64 + w * 8) * 64]); \
    GLD16(Wg + (size_t)96  * K + (k0), &Bs[buf][(96 + w * 8) * 64]); \
  } while (0)

  f32x4 acc[4][4] = {};
  const int nt = K >> 6;   // 32 for K=2048
  STG(0, 0);

  for (int t = 0; t < nt; ++t) {
    const int p = t & 1;
    asm volatile("s_waitcnt vmcnt(0)" ::: "memory");  // buf p issued 1 iter ago
    __builtin_amdgcn_s_barrier();
    if (t + 1 < nt) STG(p ^ 1, (t + 1) << 6);

    const unsigned short* At = &As[p][0];
    const unsigned short* Bt = &Bs[p][0];
#pragma unroll
    for (int kh = 0; kh < 2; ++kh) {
      bf16x8 af[4], wf[4];
#pragma unroll
      for (int m = 0; m < 4; m++) {
        const int row = wm * 64 + m * 16 + lr;
        af[m] = *(const bf16x8*)&At[row * 64 + (((g + 4 * kh) ^ (row & 7)) << 3)];
      }
#pragma unroll
      for (int n = 0; n < 4; n++) {
        const int row = wn * 64 + n * 16 + lr;
        wf[n] = *(const bf16x8*)&Bt[row * 64 + (((g + 4 * kh) ^ (row & 7)) << 3)];
      }
      __builtin_amdgcn_s_setprio(1);
#pragma unroll
      for (int m = 0; m < 4; m++)
#pragma unroll
        for (int n = 0; n < 4; n++)
          acc[m][n] = __builtin_amdgcn_mfma_f32_16x16x32_bf16(af[m], wf[n], acc[m][n], 0, 0, 0);
      __builtin_amdgcn_s_setprio(0);
    }
  }
#undef STG

  // ---- epilogue. C/D layout: col = lane&15, row = 4*(lane>>4)+reg ----
  if (EPI == 0) {
#pragma unroll
    for (int m = 0; m < 4; m++) {
      const int row = bm + wm * 64 + m * 16 + g * 4;
#pragma unroll
      for (int n = 0; n < 4; n++) {
        const int col = bn + wn * 64 + n * 16 + lr;
#pragma unroll
        for (int r = 0; r < 4; r++)
          Cf[(size_t)(row + r) * N + col] = acc[m][n][r];
      }
    }
  } else {
    // segments (BN=128 never straddles): [0,2048)=q, [2048,2304)=k, [2304,2560)=v
    const int seg = (bn < 2048) ? 0 : (bn < 2304 ? 1 : 2);
#pragma unroll
    for (int m = 0; m < 4; m++) {
#pragma unroll
      for (int n = 0; n < 4; n++) {
        const int col = bn + wn * 64 + n * 16 + lr;
        const int d   = col & 63;
#pragma unroll
        for (int r = 0; r < 4; r++) {
          const int row = bm + wm * 64 + m * 16 + g * 4 + r;
          const int tt  = row & (T_ - 1);
          const int bb  = row >> 11;
          const float val = acc[m][n][r];
          if (seg == 2) {
            const int hk = (col >> 6) - 36;
            const size_t idx = ((size_t)(bb * HK_ + hk) * T_ + tt) * D_ + d;
            voutf[idx] = val;
            const int tm   = tt & 15;
            const int tpos = (tt & ~15) | ((tm & 3) + ((tm >> 3) << 2) + ((tm & 4) << 1));
            vtb[((size_t)(bb * HK_ + hk) * D_ + d) * T_ + tpos] = f2bf(val);
          } else {
            const float cs = cosT[tt * D_ + d];
            const float sn = sinT[tt * D_ + d];
            const float other = __shfl_xor(val, 1);
            const float o = val * cs + ((lr & 1) ? other : -other) * sn;
            if (seg == 0) {
              const int h = col >> 6;
              qb[((size_t)(bb * H_ + h) * T_ + tt) * D_ + d] = f2bf(o);
            } else {
              const int hk = (col >> 6) - 32;
              const size_t idx = ((size_t)(bb * HK_ + hk) * T_ + tt) * D_ + d;
              koutf[idx] = o;
              kbf[idx]   = f2bf(o);
            }
          }
        }
      }
    }
  }
}

// ---------------------------------------------------------------------------
// Flash attention v4 (unchanged from round 5/6)
// ---------------------------------------------------------------------------
__global__ __launch_bounds__(512, 4)
void gqa_attn4(const unsigned short* __restrict__ qb,
               const unsigned short* __restrict__ kb,
               const unsigned short* __restrict__ vt,
               unsigned short* __restrict__ ob) {
  __shared__ unsigned short Ks[3][4096];
  __shared__ unsigned short Vs[3][4096];

  const int tid  = threadIdx.x;
  const int lane = tid & 63;
  const int w    = tid >> 6;
  const int qi   = lane & 31;
  const int hi   = lane >> 5;

  const int qt = 63 - (int)(blockIdx.x >> 3);
  const int go = blockIdx.x & 7;
  const int b  = go >> 2;
  const int hk = go & 3;
  const int h  = hk * 8 + w;
  const int bh = b * H_ + h;

  const int qbase = qt * 32;
  const int qrow  = qbase + qi;

  const unsigned short* qptr = qb + ((size_t)bh * T_ + qrow) * D_ + 8 * hi;
  bf16x8 qf[4];
#pragma unroll
  for (int c = 0; c < 4; c++) qf[c] = *(const bf16x8*)(qptr + 16 * c);

  const int srow   = lane >> 3;
  const int schunk = (lane & 7) ^ srow;
  const int krow   = 8 * w + srow;
  const unsigned short* gK = kb + (size_t)(b * HK_ + hk) * T_ * D_ + (size_t)krow * D_ + schunk * 8;
  const unsigned short* gV = vt + (size_t)(b * HK_ + hk) * D_ * T_ + (size_t)krow * T_ + schunk * 8;
  unsigned short* ldsK = &Ks[0][w * 512];
  unsigned short* ldsV = &Vs[0][w * 512];

#define STAGE_KV(pp, kk0) do { \
    GLD16(gK + (size_t)(kk0) * D_, ldsK + (pp) * 4096); \
    GLD16(gV + (kk0),              ldsV + (pp) * 4096); \
  } while (0)

  f32x16 o0 = {}, o1 = {};
  float m = -1e30f, l = 0.f;
  float c1 = 0.f;
  const float SC   = 0.125f * 1.44269504089f;
  const float THRR = 44.3614195f;
  const int   swz  = qi & 7;

  const int nt = ((qbase + 31) >> 6) + 1;
  STAGE_KV(0, 0);
  if (nt > 1) STAGE_KV(1, 64);

  int p = 0;
  for (int it = 0; it < nt; ++it) {
    const int kb0 = it * 64;
    const bool last = (it == nt - 1);
    const bool has1 = (kb0 + 32 <= qbase + 31);

    asm volatile("s_waitcnt lgkmcnt(0)" ::: "memory");
    if (it + 1 < nt) asm volatile("s_waitcnt vmcnt(2)" ::: "memory");
    else             asm volatile("s_waitcnt vmcnt(0)" ::: "memory");
    asm volatile("s_barrier" ::: "memory");
    if (it + 2 < nt) STAGE_KV((p + 2 > 2) ? p - 1 : p + 2, kb0 + 128);

    const unsigned short* Kt = &Ks[0][0] + p * 4096;
    const unsigned short* Vt = &Vs[0][0] + p * 4096;

    f32x16 st0 = {}, st1 = {};
    __builtin_amdgcn_s_setprio(1);
#pragma unroll
    for (int c = 0; c < 4; c++) {
      bf16x8 kf = *(const bf16x8*)&Kt[qi * 64 + (((hi + 2 * c) ^ swz) << 3)];
      st0 = __builtin_amdgcn_mfma_f32_32x32x16_bf16(kf, qf[c], st0, 0, 0, 0);
    }
    if (!last || has1) {
#pragma unroll
      for (int c = 0; c < 4; c++) {
        bf16x8 kf = *(const bf16x8*)&Kt[(32 + qi) * 64 + (((hi + 2 * c) ^ swz) << 3)];
        st1 = __builtin_amdgcn_mfma_f32_32x32x16_bf16(kf, qf[c], st1, 0, 0, 0);
      }
    }
    __builtin_amdgcn_s_setprio(0);

    if (last) {
#pragma unroll
      for (int r = 0; r < 16; ++r) {
        const int key = kb0 + (r & 3) + 8 * (r >> 2) + 4 * hi;
        st0[r] = (key      <= qrow) ? st0[r] : -1e30f;
        st1[r] = (key + 32 <= qrow) ? st1[r] : -1e30f;
      }
    }

    float tmax = fmaxf(st0[0], st0[1]);
#pragma unroll
    for (int r = 2; r < 16; ++r) tmax = fmaxf(tmax, st0[r]);
#pragma unroll
    for (int r = 0; r < 16; ++r) tmax = fmaxf(tmax, st1[r]);
    tmax = fmaxf(tmax, __shfl_xor(tmax, 32));

    if (!__all(tmax <= m + THRR)) {
      const float mnew  = fmaxf(m, tmax);
      const float al    = __builtin_amdgcn_exp2f((m - mnew) * SC);
#pragma unroll
      for (int r = 0; r < 16; ++r) { o0[r] *= al; o1[r] *= al; }
      l *= al;
      m  = mnew;
      c1 = -m * SC;
    }

    float sum = 0.f;
#pragma unroll
    for (int r = 0; r < 16; ++r) { float pv = __builtin_amdgcn_exp2f(__builtin_fmaf(st0[r], SC, c1)); st0[r] = pv; sum += pv; }
#pragma unroll
    for (int r = 0; r < 16; ++r) { float pv = __builtin_amdgcn_exp2f(__builtin_fmaf(st1[r], SC, c1)); st1[r] = pv; sum += pv; }
    sum += __shfl_xor(sum, 32);
    l += sum;

    union U8 { bf16x8 v; unsigned int u[4]; };
    U8 pf[4];
#pragma unroll
    for (int j = 0; j < 4; ++j) {
      pf[0].u[j] = cvtpk(st0[2 * j],     st0[2 * j + 1]);
      pf[1].u[j] = cvtpk(st0[8 + 2 * j], st0[8 + 2 * j + 1]);
      pf[2].u[j] = cvtpk(st1[2 * j],     st1[2 * j + 1]);
      pf[3].u[j] = cvtpk(st1[8 + 2 * j], st1[8 + 2 * j + 1]);
    }

    const int ncf = (!last || has1) ? 4 : 2;
    __builtin_amdgcn_s_setprio(1);
#pragma unroll
    for (int dh = 0; dh < 2; ++dh) {
      const unsigned short* Vrow = &Vt[(dh * 32 + qi) * 64];
      f32x16 oc = dh ? o1 : o0;
#pragma unroll
      for (int c = 0; c < 4; ++c) {
        if (c >= ncf) break;
        bf16x8 vf = *(const bf16x8*)&Vrow[(((2 * c + hi) ^ swz) << 3)];
        oc = __builtin_amdgcn_mfma_f32_32x32x16_bf16(vf, pf[c].v, oc, 0, 0, 0);
      }
      if (dh) o1 = oc; else o0 = oc;
    }
    __builtin_amdgcn_s_setprio(0);

    p = (p > 1) ? 0 : p + 1;
  }

  const float inv = 1.0f / l;
  unsigned short* orow = ob + (size_t)(b * T_ + qrow) * (H_ * D_) + h * D_;
#pragma unroll
  for (int dh = 0; dh < 2; ++dh) {
    const f32x16 ov = dh ? o1 : o0;
#pragma unroll
    for (int rg = 0; rg < 4; ++rg) {
      const int d0 = 32 * dh + 8 * rg + 4 * hi;
      ushort4 pk;
      pk.x = f2bf(ov[4 * rg + 0] * inv);
      pk.y = f2bf(ov[4 * rg + 1] * inv);
      pk.z = f2bf(ov[4 * rg + 2] * inv);
      pk.w = f2bf(ov[4 * rg + 3] * inv);
      *(ushort4*)(orow + d0) = pk;
    }
  }
#undef STAGE_KV
}

// ---------------------------------------------------------------------------
extern "C" void kernel_launch(void* const* d_in, const int* in_sizes, int n_in,
                              void* d_out, int out_size, void* d_ws, size_t ws_size,
                              hipStream_t stream) {
  const float* x    = (const float*)d_in[0];
  const float* cosT = (const float*)d_in[1];
  const float* sinT = (const float*)d_in[2];
  const float* wq   = (const float*)d_in[3];
  const float* wk   = (const float*)d_in[4];
  const float* wv   = (const float*)d_in[5];
  const float* wo   = (const float*)d_in[6];

  float* y    = (float*)d_out;                                  // B*T*C
  float* kout = (float*)d_out + (size_t)B_ * T_ * C_;           // B*Hk*T*D f32
  float* vout = kout + (size_t)B_ * HK_ * T_ * D_;              // B*Hk*T*D f32

  // Workspace (peak 56,623,104 B):
  //  [0,16M)   x_bf  -> (after QKV GEMM) o_bf
  //  [16M,26M) wqkv
  //  [26M,42M) q_bf   [42M,44M) k_bf   [44M,46M) v_t   [46M,54M) wo_bf
  char* ws = (char*)d_ws;
  unsigned short* x_bf = (unsigned short*)(ws);                 // 16,777,216
  unsigned short* o_bf = x_bf;                                  // reuse after QKV
  unsigned short* wqkv = (unsigned short*)(ws + 16777216);      // 10,485,760
  unsigned short* q_bf = (unsigned short*)(ws + 27262976);      // 16,777,216
  unsigned short* k_bf = (unsigned short*)(ws + 44040192);      //  2,097,152
  unsigned short* v_t  = (unsigned short*)(ws + 46137344);      //  2,097,152
  unsigned short* wo_bf= (unsigned short*)(ws + 48234496);      //  8,388,608 -> 56,623,104

  const int M = B_ * T_;  // 4096

  f32_to_bf16<<<8192, 256, 0, stream>>>(x,  x_bf, 2097152);
  f32_to_bf16<<<4096, 256, 0, stream>>>(wq, wqkv,               1048576);
  f32_to_bf16<<<512,  256, 0, stream>>>(wk, wqkv + 2048 * 2048, 131072);
  f32_to_bf16<<<512,  256, 0, stream>>>(wv, wqkv + 2304 * 2048, 131072);
  f32_to_bf16<<<4096, 256, 0, stream>>>(wo, wo_bf,              1048576);

  // QKV GEMM with fused RoPE-q/k + v reorder epilogue
  gemm128<1><<<dim3(2560 / 128, M / 128), 256, 0, stream>>>(
      x_bf, wqkv, M, 2560, C_, nullptr, cosT, sinT, q_bf, k_bf, v_t, kout, vout);

  gqa_attn4<<<512, 512, 0, stream>>>(q_bf, k_bf, v_t, o_bf);

  // WO GEMM, plain f32 epilogue
  gemm128<0><<<dim3(C_ / 128, M / 128), 256, 0, stream>>>(
      o_bf, wo_bf, M, C_, H_ * D_, y, nullptr, nullptr, nullptr, nullptr, nullptr, nullptr, nullptr);
}